// Round 1
// baseline (643.845 us; speedup 1.0000x reference)
//
#include <hip/hip_runtime.h>
#include <cstdint>

// ---- problem dims ----
constexpr int NB = 512, NTAU = 4, ND = 5, NDX = 256, NDZ = 16, NH = 64;
constexpr int NM  = ND * NDZ;          // 80
constexpr int NTM = NTAU * NM;         // 320
constexpr int NSAMP = NB * NTAU + NB;  // 2560 (past samples then t samples)
constexpr float LOG2PI_F = 1.8378770664093453f;

// ---- counter-based RNG (distribution-exact stand-in for jax.random) ----
__device__ __forceinline__ unsigned long long mix64(unsigned long long z) {
  z += 0x9E3779B97F4A7C15ull;
  z = (z ^ (z >> 30)) * 0xBF58476D1CE4E5B9ull;
  z = (z ^ (z >> 27)) * 0x94D049BB133111EBull;
  return z ^ (z >> 31);
}
__device__ __forceinline__ float u01f(unsigned long long h) {
  // 24-bit mantissa uniform in (0,1)
  return ((float)(unsigned)(h >> 40) + 0.5f) * (1.0f / 16777216.0f);
}
__device__ __forceinline__ float rng_normal(unsigned long long salt, unsigned long long idx) {
  float u1 = u01f(mix64(salt + 2ull * idx));
  float u2 = u01f(mix64(salt + 2ull * idx + 1ull));
  float r = sqrtf(-2.0f * logf(u1));
  return r * cosf(6.283185307179586f * u2);
}
constexpr unsigned long long SALT_ADJ = 0x1000000000000ull;
constexpr unsigned long long SALT_EP  = 0x2000000000000ull;
constexpr unsigned long long SALT_ET  = 0x3000000000000ull;

// =====================================================================
// K1: encoder for x (past) and y (t): mu = W1 . leaky(W0 . (w_enc*x) + b0) + b1
// grid (NSAMP/16, ND), block 256
// =====================================================================
__global__ __launch_bounds__(256) void k_encode(
    const float* __restrict__ x, const float* __restrict__ y,
    const float* __restrict__ w_enc, const float* __restrict__ W0,
    const float* __restrict__ b0, const float* __restrict__ W1,
    const float* __restrict__ b1, const float* __restrict__ lve,
    float* __restrict__ z_past, float* __restrict__ mu_t, float* __restrict__ z_t)
{
  __shared__ __align__(16) float xs[16][NDX];    // 16 KB
  __shared__ __align__(16) float we[NDZ][NDX];   // 16 KB
  __shared__ __align__(16) float w0c[64][NH];    // 16 KB chunk of W0[z]
  __shared__ __align__(16) float w1s[NDZ][NH];   // 4 KB
  __shared__ float mu_s[16][NDZ];                // 1 KB

  const int d  = blockIdx.y;
  const int s0 = blockIdx.x * 16;
  const int tid = threadIdx.x;

  for (int idx = tid; idx < 16 * NDX; idx += 256) {
    int s = s0 + (idx >> 8); int xx = idx & 255;
    float v = (s < NB * NTAU) ? x[((size_t)s * ND + d) * NDX + xx]
                              : y[((size_t)(s - NB * NTAU) * ND + d) * NDX + xx];
    xs[idx >> 8][xx] = v;
  }
  for (int idx = tid; idx < NDZ * NDX; idx += 256)
    we[idx >> 8][idx & 255] = w_enc[(size_t)d * NDZ * NDX + idx];
  for (int idx = tid; idx < NDZ * NH; idx += 256)
    w1s[idx >> 6][idx & 63] = W1[idx];

  const int h  = tid & 63;
  const int wv = tid >> 6;   // wave id 0..3 -> samples wv*4..wv*4+3

  for (int z = 0; z < NDZ; ++z) {
    float acc0 = 0.f, acc1 = 0.f, acc2 = 0.f, acc3 = 0.f;
    for (int x0 = 0; x0 < NDX; x0 += 64) {
      __syncthreads();
      for (int idx = tid; idx < 64 * NH; idx += 256)
        w0c[idx >> 6][idx & 63] = W0[((size_t)z * NDX + x0 + (idx >> 6)) * NH + (idx & 63)];
      __syncthreads();
      #pragma unroll 4
      for (int xi = 0; xi < 64; xi += 4) {
        float4 wev = *(const float4*)&we[z][x0 + xi];
        float p0 = wev.x * w0c[xi + 0][h];
        float p1 = wev.y * w0c[xi + 1][h];
        float p2 = wev.z * w0c[xi + 2][h];
        float p3 = wev.w * w0c[xi + 3][h];
        float4 a0 = *(const float4*)&xs[wv * 4 + 0][x0 + xi];
        float4 a1 = *(const float4*)&xs[wv * 4 + 1][x0 + xi];
        float4 a2 = *(const float4*)&xs[wv * 4 + 2][x0 + xi];
        float4 a3 = *(const float4*)&xs[wv * 4 + 3][x0 + xi];
        acc0 += a0.x * p0 + a0.y * p1 + a0.z * p2 + a0.w * p3;
        acc1 += a1.x * p0 + a1.y * p1 + a1.z * p2 + a1.w * p3;
        acc2 += a2.x * p0 + a2.y * p1 + a2.z * p2 + a2.w * p3;
        acc3 += a3.x * p0 + a3.y * p1 + a3.z * p2 + a3.w * p3;
      }
    }
    float b0v = b0[z * NH + h];
    float w1v = w1s[z][h];
    float h0 = acc0 + b0v, h1 = acc1 + b0v, h2 = acc2 + b0v, h3 = acc3 + b0v;
    h0 = fmaxf(h0, 0.01f * h0); h1 = fmaxf(h1, 0.01f * h1);
    h2 = fmaxf(h2, 0.01f * h2); h3 = fmaxf(h3, 0.01f * h3);
    float c0 = h0 * w1v, c1 = h1 * w1v, c2 = h2 * w1v, c3 = h3 * w1v;
    #pragma unroll
    for (int off = 32; off; off >>= 1) {
      c0 += __shfl_xor(c0, off, 64);
      c1 += __shfl_xor(c1, off, 64);
      c2 += __shfl_xor(c2, off, 64);
      c3 += __shfl_xor(c3, off, 64);
    }
    if (h == 0) {
      mu_s[wv * 4 + 0][z] = c0; mu_s[wv * 4 + 1][z] = c1;
      mu_s[wv * 4 + 2][z] = c2; mu_s[wv * 4 + 3][z] = c3;
    }
  }
  __syncthreads();

  // 256 threads -> (sample, z); add b1, add noise, write
  const int sl = tid >> 4, zz = tid & 15;
  const int s = s0 + sl;
  float mu = mu_s[sl][zz] + b1[zz];
  float qs = expf(0.5f * lve[d]);
  if (s < NB * NTAU) {
    unsigned long long idx = (unsigned long long)s * NM + d * NDZ + zz;
    float eps = rng_normal(SALT_EP, idx);
    z_past[(size_t)s * NM + d * NDZ + zz] = mu + qs * eps;
  } else {
    int b = s - NB * NTAU;
    unsigned long long idx = (unsigned long long)b * NM + d * NDZ + zz;
    float eps = rng_normal(SALT_ET, idx);
    size_t o = (size_t)b * NM + d * NDZ + zz;
    mu_t[o] = mu;
    z_t[o]  = mu + qs * eps;
  }
}

// =====================================================================
// K2: transition MLP + analytic KL partial sums
// grid (NM, NB/32), block 256
// =====================================================================
__global__ __launch_bounds__(256) void k_transition(
    const float* __restrict__ mask_param, const float* __restrict__ tW0,
    const float* __restrict__ tb0, const float* __restrict__ tW1,
    const float* __restrict__ tb1, const float* __restrict__ lve,
    const float* __restrict__ t_logvar,
    const float* __restrict__ z_past, const float* __restrict__ mu_t,
    float* __restrict__ kl_partial)
{
  __shared__ __align__(16) float gated[32][NTM];  // 40 KB
  __shared__ __align__(16) float w0c[64][NH];     // 16 KB
  __shared__ float mpr[NTM];                      // 1.25 KB
  __shared__ float klb[4];

  const int m   = blockIdx.x;        // 0..79
  const int b0i = blockIdx.y * 32;
  const int tid = threadIdx.x;

  for (int i = tid; i < NTM; i += 256) {
    int t = i / NM, s = i % NM;
    mpr[i] = mask_param[((size_t)t * NM + m) * NM + s];
  }
  __syncthreads();

  // build gated[b][t*M+s] = sigmoid(mask + logistic_noise) * z_past
  for (int idx = tid; idx < 32 * NTM; idx += 256) {
    int bl = idx / NTM, i = idx % NTM;
    int t = i / NM, s = i % NM;
    int b = b0i + bl;
    unsigned long long ai =
        ((unsigned long long)((b * NTAU + t) * NM + m)) * NM + s;
    float u = u01f(mix64(SALT_ADJ + ai));
    u = fminf(fmaxf(u, 1e-6f), 1.0f - 1e-6f);
    float lo  = logf(u) - log1pf(-u);
    float a   = mpr[i] + lo;
    float adj = 1.0f / (1.0f + expf(-a));
    float zp  = z_past[(size_t)(b * NTAU + t) * NM + s];
    gated[bl][i] = adj * zp;
  }

  const int h = tid & 63, wv = tid >> 6;  // wave -> 8 b's
  float acc[8] = {0, 0, 0, 0, 0, 0, 0, 0};
  for (int i0 = 0; i0 < NTM; i0 += 64) {
    __syncthreads();
    for (int idx = tid; idx < 64 * NH; idx += 256)
      w0c[idx >> 6][idx & 63] = tW0[((size_t)m * NTM + i0 + (idx >> 6)) * NH + (idx & 63)];
    __syncthreads();
    #pragma unroll 4
    for (int ii = 0; ii < 64; ii += 4) {
      float w0a = w0c[ii + 0][h], w0b = w0c[ii + 1][h];
      float w0e = w0c[ii + 2][h], w0d = w0c[ii + 3][h];
      #pragma unroll
      for (int j = 0; j < 8; ++j) {
        float4 g = *(const float4*)&gated[wv * 8 + j][i0 + ii];
        acc[j] += g.x * w0a + g.y * w0b + g.z * w0e + g.w * w0d;
      }
    }
  }

  float b0v = tb0[m * NH + h];
  float w1v = tW1[m * NH + h];
  float c[8];
  #pragma unroll
  for (int j = 0; j < 8; ++j) {
    float hv = acc[j] + b0v;
    hv = fmaxf(hv, 0.01f * hv);
    c[j] = hv * w1v;
  }
  #pragma unroll
  for (int off = 32; off; off >>= 1) {
    #pragma unroll
    for (int j = 0; j < 8; ++j) c[j] += __shfl_xor(c[j], off, 64);
  }

  if (h == 0) {
    int d = m / NDZ;
    float lv_t = t_logvar[m];
    float lv_e = lve[d];
    float inv2var = 0.5f * expf(-lv_t);
    float qvar = expf(lv_e);
    float cterm = 0.5f * lv_t - 0.5f * lv_e - 0.5f;
    float bv = tb1[m];
    float klw = 0.0f;
    #pragma unroll
    for (int j = 0; j < 8; ++j) {
      int b = b0i + wv * 8 + j;
      float pz = c[j] + bv;
      float diff = mu_t[(size_t)b * NM + m] - pz;
      klw += cterm + (qvar + diff * diff) * inv2var;
    }
    klb[wv] = klw;
  }
  __syncthreads();
  if (tid == 0)
    kl_partial[blockIdx.y * gridDim.x + blockIdx.x] = klb[0] + klb[1] + klb[2] + klb[3];
}

// =====================================================================
// K3: decoder MLP + gaussian recon log-lik partial sums
// grid (NDX, ND), block 256
// =====================================================================
__global__ __launch_bounds__(256) void k_decoder(
    const float* __restrict__ y, const float* __restrict__ w_dec,
    const float* __restrict__ dW0, const float* __restrict__ db0,
    const float* __restrict__ dW1, const float* __restrict__ db1,
    const float* __restrict__ lvd, const float* __restrict__ z_t,
    float* __restrict__ rec_partial)
{
  __shared__ __align__(16) float w0s[NDZ][NH];  // 4 KB
  __shared__ float wd[NDZ];
  __shared__ float rb[4];

  const int xx = blockIdx.x;   // 0..255
  const int d  = blockIdx.y;
  const int tid = threadIdx.x;

  for (int idx = tid; idx < NDZ * NH; idx += 256)
    w0s[idx >> 6][idx & 63] = dW0[((size_t)xx * NDZ + (idx >> 6)) * NH + (idx & 63)];
  if (tid < NDZ) wd[tid] = w_dec[((size_t)d * NDX + xx) * NDZ + tid];
  __syncthreads();

  const int h = tid & 63, wv = tid >> 6;
  const float b0v = db0[xx * NH + h];
  const float w1v = dW1[xx * NH + h];
  const float b1v = db1[xx];
  const float lv = lvd[d];
  const float inv_std = expf(-0.5f * lv);
  const float cterm = -0.5f * lv - 0.5f * LOG2PI_F;

  float racc = 0.0f;
  for (int b = wv; b < NB; b += 4) {
    const float* ztp = z_t + (size_t)b * NM + d * NDZ;
    float a = 0.0f;
    #pragma unroll
    for (int z = 0; z < NDZ; ++z)
      a += (wd[z] * ztp[z]) * w0s[z][h];
    float hv = a + b0v;
    hv = fmaxf(hv, 0.01f * hv);
    float c = hv * w1v;
    #pragma unroll
    for (int off = 32; off; off >>= 1) c += __shfl_xor(c, off, 64);
    if (h == 0) {
      float px = c + b1v;
      float e = (y[((size_t)b * ND + d) * NDX + xx] - px) * inv_std;
      racc += -0.5f * e * e + cterm;
    }
  }
  if (h == 0) rb[wv] = racc;
  __syncthreads();
  if (tid == 0) rec_partial[blockIdx.y * gridDim.x + blockIdx.x] = rb[0] + rb[1] + rb[2] + rb[3];
}

// =====================================================================
// K4: final reduction -> loss = (sum_kl - sum_recon) / B
// =====================================================================
__global__ __launch_bounds__(256) void k_reduce(
    const float* __restrict__ rp, const float* __restrict__ kp,
    float* __restrict__ out)
{
  __shared__ float sr[4], sk[4];
  float r = 0.f, k = 0.f;
  for (int i = threadIdx.x; i < 1280; i += 256) { r += rp[i]; k += kp[i]; }
  #pragma unroll
  for (int off = 32; off; off >>= 1) {
    r += __shfl_xor(r, off, 64);
    k += __shfl_xor(k, off, 64);
  }
  int wv = threadIdx.x >> 6;
  if ((threadIdx.x & 63) == 0) { sr[wv] = r; sk[wv] = k; }
  __syncthreads();
  if (threadIdx.x == 0) {
    float R = sr[0] + sr[1] + sr[2] + sr[3];
    float K = sk[0] + sk[1] + sk[2] + sk[3];
    out[0] = (K - R) / (float)NB;
  }
}

// =====================================================================
extern "C" void kernel_launch(void* const* d_in, const int* in_sizes, int n_in,
                              void* d_out, int out_size, void* d_ws, size_t ws_size,
                              hipStream_t stream) {
  (void)in_sizes; (void)n_in; (void)out_size; (void)ws_size;
  const float* x        = (const float*)d_in[0];
  const float* y        = (const float*)d_in[1];
  const float* mask_p   = (const float*)d_in[2];
  const float* w_enc    = (const float*)d_in[3];
  const float* w_dec    = (const float*)d_in[4];
  const float* enc_W0   = (const float*)d_in[5];
  const float* enc_b0   = (const float*)d_in[6];
  const float* enc_W1   = (const float*)d_in[7];
  const float* enc_b1   = (const float*)d_in[8];
  const float* dec_W0   = (const float*)d_in[9];
  const float* dec_b0   = (const float*)d_in[10];
  const float* dec_W1   = (const float*)d_in[11];
  const float* dec_b1   = (const float*)d_in[12];
  const float* t_W0     = (const float*)d_in[13];
  const float* t_b0     = (const float*)d_in[14];
  const float* t_W1     = (const float*)d_in[15];
  const float* t_b1     = (const float*)d_in[16];
  const float* lv_enc   = (const float*)d_in[17];
  const float* lv_dec   = (const float*)d_in[18];
  const float* t_logvar = (const float*)d_in[19];

  float* ws     = (float*)d_ws;
  float* z_past = ws;                                   // 512*4*80 = 163840
  float* mu_t   = z_past + (size_t)NB * NTAU * NM;      // 40960
  float* z_t    = mu_t + (size_t)NB * NM;               // 40960
  float* rec_p  = z_t + (size_t)NB * NM;                // 1280
  float* kl_p   = rec_p + 1280;                         // 1280

  k_encode<<<dim3(NSAMP / 16, ND), 256, 0, stream>>>(
      x, y, w_enc, enc_W0, enc_b0, enc_W1, enc_b1, lv_enc, z_past, mu_t, z_t);
  k_transition<<<dim3(NM, NB / 32), 256, 0, stream>>>(
      mask_p, t_W0, t_b0, t_W1, t_b1, lv_enc, t_logvar, z_past, mu_t, kl_p);
  k_decoder<<<dim3(NDX, ND), 256, 0, stream>>>(
      y, w_dec, dec_W0, dec_b0, dec_W1, dec_b1, lv_dec, z_t, rec_p);
  k_reduce<<<1, 256, 0, stream>>>(rec_p, kl_p, (float*)d_out);
}

// Round 2
// 241.753 us; speedup vs baseline: 2.6632x; 2.6632x over previous
//
#include <hip/hip_runtime.h>
#include <cstdint>

// ---- problem dims ----
constexpr int NB = 512, NTAU = 4, ND = 5, NDX = 256, NDZ = 16, NH = 64;
constexpr int NM  = ND * NDZ;          // 80
constexpr int NTM = NTAU * NM;         // 320
constexpr int NSAMP = NB * NTAU + NB;  // 2560 (past samples then t samples)
constexpr float LOG2PI_F = 1.8378770664093453f;

typedef __attribute__((ext_vector_type(8))) short bf16x8;
typedef __attribute__((ext_vector_type(4))) float f32x4;

// ---- counter-based RNG (distribution-exact stand-in for jax.random) ----
__device__ __forceinline__ unsigned long long mix64(unsigned long long z) {
  z += 0x9E3779B97F4A7C15ull;
  z = (z ^ (z >> 30)) * 0xBF58476D1CE4E5B9ull;
  z = (z ^ (z >> 27)) * 0x94D049BB133111EBull;
  return z ^ (z >> 31);
}
__device__ __forceinline__ float u01f(unsigned long long h) {
  return ((float)(unsigned)(h >> 40) + 0.5f) * (1.0f / 16777216.0f);
}
__device__ __forceinline__ float rng_normal(unsigned long long salt, unsigned long long idx) {
  float u1 = u01f(mix64(salt + 2ull * idx));
  float u2 = u01f(mix64(salt + 2ull * idx + 1ull));
  float r = sqrtf(-2.0f * logf(u1));
  return r * cosf(6.283185307179586f * u2);
}
constexpr unsigned long long SALT_ADJ = 0x1000000000000ull;
constexpr unsigned long long SALT_EP  = 0x2000000000000ull;
constexpr unsigned long long SALT_ET  = 0x3000000000000ull;

__device__ __forceinline__ short f2bf(float f) {
  unsigned u = __float_as_uint(f);
  unsigned r = (u + 0x7FFFu + ((u >> 16) & 1u)) >> 16;
  return (short)r;
}

// =====================================================================
// prep kernels: bf16 operand materialization
// =====================================================================
// Abf[d][s][xx] = bf16( s<2048 ? x[s,d,xx] : y[s-2048,d,xx] )
__global__ __launch_bounds__(256) void k_prepA(
    const float* __restrict__ x, const float* __restrict__ y, short* __restrict__ Abf)
{
  int idx = blockIdx.x * 256 + threadIdx.x;           // < 5*2560*256
  int d = idx / (NSAMP * NDX);
  int r = idx % (NSAMP * NDX);
  int s = r >> 8, xx = r & 255;
  float v = (s < NB * NTAU) ? x[((size_t)s * ND + d) * NDX + xx]
                            : y[((size_t)(s - NB * NTAU) * ND + d) * NDX + xx];
  Abf[idx] = f2bf(v);
}

// PtE[d][col=z*64+h][xx] = bf16( w_enc[d,z,xx] * enc_W0[z,xx,h] )
__global__ __launch_bounds__(256) void k_prepP(
    const float* __restrict__ w_enc, const float* __restrict__ W0, short* __restrict__ PtE)
{
  int idx = blockIdx.x * 256 + threadIdx.x;           // < 5*1024*256
  int d = idx / (1024 * NDX);
  int r = idx % (1024 * NDX);
  int col = r >> 8, xx = r & 255;
  int z = col >> 6, h = col & 63;
  float v = w_enc[((size_t)d * NDZ + z) * NDX + xx] * W0[((size_t)z * NDX + xx) * NH + h];
  PtE[idx] = f2bf(v);
}

// QtD[((d*256+xx)*64+h)][k(32, z-padded)] = bf16( w_dec[d,xx,z] * dec_W0[xx,z,h] ), 0 for k>=16
__global__ __launch_bounds__(256) void k_prepQ(
    const float* __restrict__ w_dec, const float* __restrict__ dW0, short* __restrict__ QtD)
{
  int t = blockIdx.x * 256 + threadIdx.x;             // < 5*256*64
  int d = t / (NDX * NH);
  int r = t % (NDX * NH);
  int xx = r >> 6, h = r & 63;
  size_t base = (size_t)t * 32;
  #pragma unroll
  for (int z = 0; z < NDZ; ++z)
    QtD[base + z] = f2bf(w_dec[((size_t)d * NDX + xx) * NDZ + z] *
                         dW0[((size_t)xx * NDZ + z) * NH + h]);
  #pragma unroll
  for (int z = NDZ; z < 32; ++z) QtD[base + z] = 0;
}

// =====================================================================
// encoder: C[s, z*64+h] = A[s,:] . PtE[z*64+h,:]  (MFMA), fused epilogue
// grid (2560/64, 16 z, 5 d), block 256 (4 waves x 16 rows)
// =====================================================================
__global__ __launch_bounds__(256) void k_enc_mfma(
    const short* __restrict__ Abf, const short* __restrict__ PtE,
    const float* __restrict__ b0, const float* __restrict__ W1,
    const float* __restrict__ b1, const float* __restrict__ lve,
    float* __restrict__ z_past, float* __restrict__ mu_t, float* __restrict__ z_t)
{
  const int d = blockIdx.z, zb = blockIdx.y;
  const int s0 = blockIdx.x * 64;
  const int w = threadIdx.x >> 6, l = threadIdx.x & 63;
  const int lrow = l & 15, g = l >> 4;

  const int srow = s0 + w * 16 + lrow;
  const short* Arow = Abf + ((size_t)(d * NSAMP + srow)) * NDX + g * 8;
  bf16x8 a[8];
  #pragma unroll
  for (int ks = 0; ks < 8; ++ks) a[ks] = *(const bf16x8*)(Arow + ks * 32);

  f32x4 acc[4] = {};
  #pragma unroll
  for (int nt = 0; nt < 4; ++nt) {
    const short* Brow = PtE + ((size_t)(d * 1024 + zb * 64 + nt * 16 + lrow)) * NDX + g * 8;
    #pragma unroll
    for (int ks = 0; ks < 8; ++ks) {
      bf16x8 b = *(const bf16x8*)(Brow + ks * 32);
      acc[nt] = __builtin_amdgcn_mfma_f32_16x16x32_bf16(a[ks], b, acc[nt], 0, 0, 0);
    }
  }

  // epilogue: leaky(.+b0)*W1, reduce over 64 h-cols, +b1, reparameterize
  float b0v[4], w1v[4];
  #pragma unroll
  for (int nt = 0; nt < 4; ++nt) {
    int h = nt * 16 + lrow;
    b0v[nt] = b0[zb * NH + h];
    w1v[nt] = W1[zb * NH + h];
  }
  float rsum[4];
  #pragma unroll
  for (int reg = 0; reg < 4; ++reg) {
    float v = 0.0f;
    #pragma unroll
    for (int nt = 0; nt < 4; ++nt) {
      float hv = acc[nt][reg] + b0v[nt];
      hv = fmaxf(hv, 0.01f * hv);
      v += hv * w1v[nt];
    }
    #pragma unroll
    for (int off = 1; off < 16; off <<= 1) v += __shfl_xor(v, off, 16);
    rsum[reg] = v;
  }
  if (lrow == 0) {
    float qs = expf(0.5f * lve[d]);
    float b1v = b1[zb];
    #pragma unroll
    for (int reg = 0; reg < 4; ++reg) {
      int s = s0 + w * 16 + g * 4 + reg;
      float mu = rsum[reg] + b1v;
      if (s < NB * NTAU) {
        unsigned long long idx = (unsigned long long)s * NM + d * NDZ + zb;
        float eps = rng_normal(SALT_EP, idx);
        z_past[(size_t)s * NM + d * NDZ + zb] = mu + qs * eps;
      } else {
        int b = s - NB * NTAU;
        unsigned long long idx = (unsigned long long)b * NM + d * NDZ + zb;
        float eps = rng_normal(SALT_ET, idx);
        size_t o = (size_t)b * NM + d * NDZ + zb;
        mu_t[o] = mu;
        z_t[o]  = mu + qs * eps;
      }
    }
  }
}

// =====================================================================
// decoder: hd[b, xx*64+h] = zt[b, d,:16] . QtD  (K=32 padded MFMA), fused recon
// grid (2, 256 xx, 5 d), block 256 (4 waves x 64 rows)
// =====================================================================
__global__ __launch_bounds__(256) void k_dec_mfma(
    const float* __restrict__ zt, const short* __restrict__ QtD,
    const float* __restrict__ y, const float* __restrict__ db0,
    const float* __restrict__ dW1, const float* __restrict__ db1,
    const float* __restrict__ lvd, float* __restrict__ rec_partial)
{
  const int d = blockIdx.z, xx = blockIdx.y, mb = blockIdx.x;
  const int w = threadIdx.x >> 6, l = threadIdx.x & 63;
  const int lrow = l & 15, g = l >> 4;

  bf16x8 bfr[4];
  const short* Bbase = QtD + ((size_t)((d * NDX + xx) * NH)) * 32;
  #pragma unroll
  for (int nt = 0; nt < 4; ++nt)
    bfr[nt] = *(const bf16x8*)(Bbase + (nt * 16 + lrow) * 32 + g * 8);

  f32x4 acc[4][4] = {};
  #pragma unroll
  for (int mt = 0; mt < 4; ++mt) {
    int b = mb * 256 + w * 64 + mt * 16 + lrow;
    bf16x8 a = {0, 0, 0, 0, 0, 0, 0, 0};
    if (g < 2) {
      const float* zp = zt + (size_t)b * NM + d * NDZ + g * 8;
      float4 f0 = *(const float4*)zp;
      float4 f1 = *(const float4*)(zp + 4);
      a[0] = f2bf(f0.x); a[1] = f2bf(f0.y); a[2] = f2bf(f0.z); a[3] = f2bf(f0.w);
      a[4] = f2bf(f1.x); a[5] = f2bf(f1.y); a[6] = f2bf(f1.z); a[7] = f2bf(f1.w);
    }
    #pragma unroll
    for (int nt = 0; nt < 4; ++nt)
      acc[mt][nt] = __builtin_amdgcn_mfma_f32_16x16x32_bf16(a, bfr[nt], acc[mt][nt], 0, 0, 0);
  }

  float db0v[4], dW1v[4];
  #pragma unroll
  for (int nt = 0; nt < 4; ++nt) {
    int h = nt * 16 + lrow;
    db0v[nt] = db0[xx * NH + h];
    dW1v[nt] = dW1[xx * NH + h];
  }
  const float lv = lvd[d];
  const float inv_std = expf(-0.5f * lv);
  const float cterm = -0.5f * lv - 0.5f * LOG2PI_F;
  const float b1v = db1[xx];

  float racc = 0.0f;
  #pragma unroll
  for (int mt = 0; mt < 4; ++mt) {
    #pragma unroll
    for (int reg = 0; reg < 4; ++reg) {
      float v = 0.0f;
      #pragma unroll
      for (int nt = 0; nt < 4; ++nt) {
        float hv = acc[mt][nt][reg] + db0v[nt];
        hv = fmaxf(hv, 0.01f * hv);
        v += hv * dW1v[nt];
      }
      #pragma unroll
      for (int off = 1; off < 16; off <<= 1) v += __shfl_xor(v, off, 16);
      if (lrow == 0) {
        int b = mb * 256 + w * 64 + mt * 16 + g * 4 + reg;
        float px = v + b1v;
        float e = (y[((size_t)b * ND + d) * NDX + xx] - px) * inv_std;
        racc += -0.5f * e * e + cterm;
      }
    }
  }
  racc += __shfl_xor(racc, 16, 64);
  racc += __shfl_xor(racc, 32, 64);

  __shared__ float rb[4];
  if (l == 0) rb[w] = racc;
  __syncthreads();
  if (threadIdx.x == 0)
    rec_partial[((size_t)d * NDX + xx) * 2 + mb] = rb[0] + rb[1] + rb[2] + rb[3];
}

// =====================================================================
// K2: transition MLP + analytic KL partial sums (unchanged, passing)
// grid (NM, NB/32), block 256
// =====================================================================
__global__ __launch_bounds__(256) void k_transition(
    const float* __restrict__ mask_param, const float* __restrict__ tW0,
    const float* __restrict__ tb0, const float* __restrict__ tW1,
    const float* __restrict__ tb1, const float* __restrict__ lve,
    const float* __restrict__ t_logvar,
    const float* __restrict__ z_past, const float* __restrict__ mu_t,
    float* __restrict__ kl_partial)
{
  __shared__ __align__(16) float gated[32][NTM];  // 40 KB
  __shared__ __align__(16) float w0c[64][NH];     // 16 KB
  __shared__ float mpr[NTM];
  __shared__ float klb[4];

  const int m   = blockIdx.x;
  const int b0i = blockIdx.y * 32;
  const int tid = threadIdx.x;

  for (int i = tid; i < NTM; i += 256) {
    int t = i / NM, s = i % NM;
    mpr[i] = mask_param[((size_t)t * NM + m) * NM + s];
  }
  __syncthreads();

  for (int idx = tid; idx < 32 * NTM; idx += 256) {
    int bl = idx / NTM, i = idx % NTM;
    int t = i / NM, s = i % NM;
    int b = b0i + bl;
    unsigned long long ai =
        ((unsigned long long)((b * NTAU + t) * NM + m)) * NM + s;
    float u = u01f(mix64(SALT_ADJ + ai));
    u = fminf(fmaxf(u, 1e-6f), 1.0f - 1e-6f);
    float lo  = logf(u) - log1pf(-u);
    float a   = mpr[i] + lo;
    float adj = 1.0f / (1.0f + expf(-a));
    float zp  = z_past[(size_t)(b * NTAU + t) * NM + s];
    gated[bl][i] = adj * zp;
  }

  const int h = tid & 63, wv = tid >> 6;
  float acc[8] = {0, 0, 0, 0, 0, 0, 0, 0};
  for (int i0 = 0; i0 < NTM; i0 += 64) {
    __syncthreads();
    for (int idx = tid; idx < 64 * NH; idx += 256)
      w0c[idx >> 6][idx & 63] = tW0[((size_t)m * NTM + i0 + (idx >> 6)) * NH + (idx & 63)];
    __syncthreads();
    #pragma unroll 4
    for (int ii = 0; ii < 64; ii += 4) {
      float w0a = w0c[ii + 0][h], w0b = w0c[ii + 1][h];
      float w0e = w0c[ii + 2][h], w0d = w0c[ii + 3][h];
      #pragma unroll
      for (int j = 0; j < 8; ++j) {
        float4 gg = *(const float4*)&gated[wv * 8 + j][i0 + ii];
        acc[j] += gg.x * w0a + gg.y * w0b + gg.z * w0e + gg.w * w0d;
      }
    }
  }

  float b0v = tb0[m * NH + h];
  float w1v = tW1[m * NH + h];
  float c[8];
  #pragma unroll
  for (int j = 0; j < 8; ++j) {
    float hv = acc[j] + b0v;
    hv = fmaxf(hv, 0.01f * hv);
    c[j] = hv * w1v;
  }
  #pragma unroll
  for (int off = 32; off; off >>= 1) {
    #pragma unroll
    for (int j = 0; j < 8; ++j) c[j] += __shfl_xor(c[j], off, 64);
  }

  if (h == 0) {
    int d = m / NDZ;
    float lv_t = t_logvar[m];
    float lv_e = lve[d];
    float inv2var = 0.5f * expf(-lv_t);
    float qvar = expf(lv_e);
    float cterm = 0.5f * lv_t - 0.5f * lv_e - 0.5f;
    float bv = tb1[m];
    float klw = 0.0f;
    #pragma unroll
    for (int j = 0; j < 8; ++j) {
      int b = b0i + wv * 8 + j;
      float pz = c[j] + bv;
      float diff = mu_t[(size_t)b * NM + m] - pz;
      klw += cterm + (qvar + diff * diff) * inv2var;
    }
    klb[wv] = klw;
  }
  __syncthreads();
  if (tid == 0)
    kl_partial[blockIdx.y * gridDim.x + blockIdx.x] = klb[0] + klb[1] + klb[2] + klb[3];
}

// =====================================================================
// K4: final reduction -> loss = (sum_kl - sum_recon) / B
// =====================================================================
__global__ __launch_bounds__(256) void k_reduce(
    const float* __restrict__ rp, const float* __restrict__ kp,
    float* __restrict__ out)
{
  __shared__ float sr[4], sk[4];
  float r = 0.f, k = 0.f;
  for (int i = threadIdx.x; i < 2560; i += 256) r += rp[i];
  for (int i = threadIdx.x; i < 1280; i += 256) k += kp[i];
  #pragma unroll
  for (int off = 32; off; off >>= 1) {
    r += __shfl_xor(r, off, 64);
    k += __shfl_xor(k, off, 64);
  }
  int wv = threadIdx.x >> 6;
  if ((threadIdx.x & 63) == 0) { sr[wv] = r; sk[wv] = k; }
  __syncthreads();
  if (threadIdx.x == 0) {
    float R = sr[0] + sr[1] + sr[2] + sr[3];
    float K = sk[0] + sk[1] + sk[2] + sk[3];
    out[0] = (K - R) / (float)NB;
  }
}

// =====================================================================
extern "C" void kernel_launch(void* const* d_in, const int* in_sizes, int n_in,
                              void* d_out, int out_size, void* d_ws, size_t ws_size,
                              hipStream_t stream) {
  (void)in_sizes; (void)n_in; (void)out_size; (void)ws_size;
  const float* x        = (const float*)d_in[0];
  const float* y        = (const float*)d_in[1];
  const float* mask_p   = (const float*)d_in[2];
  const float* w_enc    = (const float*)d_in[3];
  const float* w_dec    = (const float*)d_in[4];
  const float* enc_W0   = (const float*)d_in[5];
  const float* enc_b0   = (const float*)d_in[6];
  const float* enc_W1   = (const float*)d_in[7];
  const float* enc_b1   = (const float*)d_in[8];
  const float* dec_W0   = (const float*)d_in[9];
  const float* dec_b0   = (const float*)d_in[10];
  const float* dec_W1   = (const float*)d_in[11];
  const float* dec_b1   = (const float*)d_in[12];
  const float* t_W0     = (const float*)d_in[13];
  const float* t_b0     = (const float*)d_in[14];
  const float* t_W1     = (const float*)d_in[15];
  const float* t_b1     = (const float*)d_in[16];
  const float* lv_enc   = (const float*)d_in[17];
  const float* lv_dec   = (const float*)d_in[18];
  const float* t_logvar = (const float*)d_in[19];

  float* ws     = (float*)d_ws;
  float* z_past = ws;                       // 163840 f32
  float* mu_t   = z_past + 163840;          // 40960
  float* z_t    = mu_t + 40960;             // 40960
  float* rec_p  = z_t + 40960;              // 2560
  float* kl_p   = rec_p + 2560;             // 1280
  short* Abf    = (short*)(kl_p + 1280);    // 5*2560*256 bf16
  short* PtE    = Abf + 5 * NSAMP * NDX;    // 5*1024*256 bf16
  short* QtD    = PtE + 5 * 1024 * NDX;     // 5*256*64*32 bf16

  k_prepA<<<5 * NSAMP * NDX / 256, 256, 0, stream>>>(x, y, Abf);
  k_prepP<<<5 * 1024 * NDX / 256, 256, 0, stream>>>(w_enc, enc_W0, PtE);
  k_prepQ<<<5 * NDX * NH / 256, 256, 0, stream>>>(w_dec, dec_W0, QtD);

  k_enc_mfma<<<dim3(NSAMP / 64, NDZ, ND), 256, 0, stream>>>(
      Abf, PtE, enc_b0, enc_W1, enc_b1, lv_enc, z_past, mu_t, z_t);
  k_transition<<<dim3(NM, NB / 32), 256, 0, stream>>>(
      mask_p, t_W0, t_b0, t_W1, t_b1, lv_enc, t_logvar, z_past, mu_t, kl_p);
  k_dec_mfma<<<dim3(2, NDX, ND), 256, 0, stream>>>(
      z_t, QtD, y, dec_b0, dec_W1, dec_b1, lv_dec, rec_p);
  k_reduce<<<1, 256, 0, stream>>>(rec_p, kl_p, (float*)d_out);
}

// Round 3
// 168.016 us; speedup vs baseline: 3.8320x; 1.4389x over previous
//
#include <hip/hip_runtime.h>
#include <cstdint>

// ---- problem dims ----
constexpr int NB = 512, NTAU = 4, ND = 5, NDX = 256, NDZ = 16, NH = 64;
constexpr int NM  = ND * NDZ;          // 80
constexpr int NTM = NTAU * NM;         // 320
constexpr int NSAMP = NB * NTAU + NB;  // 2560 (past samples then t samples)
constexpr float LOG2PI_F = 1.8378770664093453f;

typedef __attribute__((ext_vector_type(8))) short bf16x8;
typedef __attribute__((ext_vector_type(4))) float f32x4;

// ---- counter-based RNG (distribution-exact stand-in for jax.random) ----
__device__ __forceinline__ unsigned long long mix64(unsigned long long z) {
  z += 0x9E3779B97F4A7C15ull;
  z = (z ^ (z >> 30)) * 0xBF58476D1CE4E5B9ull;
  z = (z ^ (z >> 27)) * 0x94D049BB133111EBull;
  return z ^ (z >> 31);
}
__device__ __forceinline__ float u01f(unsigned long long h) {
  return ((float)(unsigned)(h >> 40) + 0.5f) * (1.0f / 16777216.0f);
}
__device__ __forceinline__ float rng_normal(unsigned long long salt, unsigned long long idx) {
  float u1 = u01f(mix64(salt + 2ull * idx));
  float u2 = u01f(mix64(salt + 2ull * idx + 1ull));
  float r = sqrtf(-2.0f * logf(u1));
  return r * cosf(6.283185307179586f * u2);
}
constexpr unsigned long long SALT_ADJ = 0x1000000000000ull;
constexpr unsigned long long SALT_EP  = 0x2000000000000ull;
constexpr unsigned long long SALT_ET  = 0x3000000000000ull;

__device__ __forceinline__ short f2bf(float f) {
  unsigned u = __float_as_uint(f);
  unsigned r = (u + 0x7FFFu + ((u >> 16) & 1u)) >> 16;
  return (short)r;
}

// =====================================================================
// prep kernels: bf16 operand materialization
// =====================================================================
__global__ __launch_bounds__(256) void k_prepA(
    const float* __restrict__ x, const float* __restrict__ y, short* __restrict__ Abf)
{
  int idx = blockIdx.x * 256 + threadIdx.x;
  int d = idx / (NSAMP * NDX);
  int r = idx % (NSAMP * NDX);
  int s = r >> 8, xx = r & 255;
  float v = (s < NB * NTAU) ? x[((size_t)s * ND + d) * NDX + xx]
                            : y[((size_t)(s - NB * NTAU) * ND + d) * NDX + xx];
  Abf[idx] = f2bf(v);
}

__global__ __launch_bounds__(256) void k_prepP(
    const float* __restrict__ w_enc, const float* __restrict__ W0, short* __restrict__ PtE)
{
  int idx = blockIdx.x * 256 + threadIdx.x;
  int d = idx / (1024 * NDX);
  int r = idx % (1024 * NDX);
  int col = r >> 8, xx = r & 255;
  int z = col >> 6, h = col & 63;
  float v = w_enc[((size_t)d * NDZ + z) * NDX + xx] * W0[((size_t)z * NDX + xx) * NH + h];
  PtE[idx] = f2bf(v);
}

__global__ __launch_bounds__(256) void k_prepQ(
    const float* __restrict__ w_dec, const float* __restrict__ dW0, short* __restrict__ QtD)
{
  int t = blockIdx.x * 256 + threadIdx.x;
  int d = t / (NDX * NH);
  int r = t % (NDX * NH);
  int xx = r >> 6, h = r & 63;
  size_t base = (size_t)t * 32;
  #pragma unroll
  for (int z = 0; z < NDZ; ++z)
    QtD[base + z] = f2bf(w_dec[((size_t)d * NDX + xx) * NDZ + z] *
                         dW0[((size_t)xx * NDZ + z) * NH + h]);
  #pragma unroll
  for (int z = NDZ; z < 32; ++z) QtD[base + z] = 0;
}

// EM[t][m][s] = exp(-mask_param[t][m][s])   (25600 elems)
__global__ __launch_bounds__(256) void k_prepEM(
    const float* __restrict__ mask_param, float* __restrict__ em)
{
  int idx = blockIdx.x * 256 + threadIdx.x;
  em[idx] = expf(-mask_param[idx]);
}

// TtB[m][h][k] = bf16(t_W0[m][k][h])  via LDS transpose
// grid (5 kt, 80 m), block 256
__global__ __launch_bounds__(256) void k_prepT(
    const float* __restrict__ tW0, short* __restrict__ TtB)
{
  __shared__ short lds[64][65];
  const int m = blockIdx.y, k0 = blockIdx.x * 64;
  for (int idx = threadIdx.x; idx < 64 * 64; idx += 256) {
    int hh = idx & 63, kk = idx >> 6;
    lds[kk][hh] = f2bf(tW0[((size_t)m * NTM + k0 + kk) * NH + hh]);
  }
  __syncthreads();
  for (int idx = threadIdx.x; idx < 64 * 64; idx += 256) {
    int kk = idx & 63, hh = idx >> 6;
    TtB[((size_t)m * NH + hh) * NTM + k0 + kk] = lds[kk][hh];
  }
}

// =====================================================================
// gated[m][b][tm] = bf16( adj(b,t,m,s) * z_past[b][tm] ),  tm = t*80+s
// adj = u / (u + em*(1-u)) with logistic-noise algebra folded in
// grid (NB, NM), block 320 (tid = tm)
// =====================================================================
__global__ __launch_bounds__(320) void k_gated(
    const float* __restrict__ em, const float* __restrict__ z_past,
    short* __restrict__ gated)
{
  const int b = blockIdx.x, m = blockIdx.y;
  const int tm = threadIdx.x;
  const int t = tm / NM, s = tm - t * NM;
  unsigned long long ai = ((unsigned long long)((b * NTAU + t) * NM + m)) * NM + s;
  float u = u01f(mix64(SALT_ADJ + ai));
  u = fminf(fmaxf(u, 1e-6f), 1.0f - 1e-6f);
  float e = em[(t * NM + m) * NM + s];
  float adj = u / (u + e * (1.0f - u));
  float zp = z_past[(size_t)b * NTM + tm];
  gated[((size_t)m * NB + b) * NTM + tm] = f2bf(adj * zp);
}

// =====================================================================
// transition GEMM + KL: pz[b, m*64+h] via MFMA over K=320, fused KL
// grid (NB/64, NM), block 256 (4 waves x 16 rows x 64 cols)
// =====================================================================
__global__ __launch_bounds__(256) void k_trans_mfma(
    const short* __restrict__ gated, const short* __restrict__ TtB,
    const float* __restrict__ tb0, const float* __restrict__ tW1,
    const float* __restrict__ tb1, const float* __restrict__ lve,
    const float* __restrict__ t_logvar, const float* __restrict__ mu_t,
    float* __restrict__ kl_partial)
{
  const int m = blockIdx.y;
  const int b0 = blockIdx.x * 64;
  const int w = threadIdx.x >> 6, l = threadIdx.x & 63;
  const int lrow = l & 15, g = l >> 4;

  const short* Arow = gated + ((size_t)(m * NB + b0 + w * 16 + lrow)) * NTM + g * 8;
  bf16x8 a[10];
  #pragma unroll
  for (int ks = 0; ks < 10; ++ks) a[ks] = *(const bf16x8*)(Arow + ks * 32);

  f32x4 acc[4] = {};
  #pragma unroll
  for (int nt = 0; nt < 4; ++nt) {
    const short* Brow = TtB + ((size_t)(m * NH + nt * 16 + lrow)) * NTM + g * 8;
    #pragma unroll
    for (int ks = 0; ks < 10; ++ks) {
      bf16x8 bv = *(const bf16x8*)(Brow + ks * 32);
      acc[nt] = __builtin_amdgcn_mfma_f32_16x16x32_bf16(a[ks], bv, acc[nt], 0, 0, 0);
    }
  }

  float b0v[4], w1v[4];
  #pragma unroll
  for (int nt = 0; nt < 4; ++nt) {
    int h = nt * 16 + lrow;
    b0v[nt] = tb0[m * NH + h];
    w1v[nt] = tW1[m * NH + h];
  }

  const int d = m >> 4;
  const float lv_t = t_logvar[m];
  const float lv_e = lve[d];
  const float inv2var = 0.5f * expf(-lv_t);
  const float qvar = expf(lv_e);
  const float cterm = 0.5f * lv_t - 0.5f * lv_e - 0.5f;
  const float bv1 = tb1[m];

  float klw = 0.0f;
  #pragma unroll
  for (int reg = 0; reg < 4; ++reg) {
    float v = 0.0f;
    #pragma unroll
    for (int nt = 0; nt < 4; ++nt) {
      float hv = acc[nt][reg] + b0v[nt];
      hv = fmaxf(hv, 0.01f * hv);
      v += hv * w1v[nt];
    }
    #pragma unroll
    for (int off = 1; off < 16; off <<= 1) v += __shfl_xor(v, off, 16);
    if (lrow == 0) {
      int b = b0 + w * 16 + g * 4 + reg;
      float pz = v + bv1;
      float diff = mu_t[(size_t)b * NM + m] - pz;
      klw += cterm + (qvar + diff * diff) * inv2var;
    }
  }
  klw += __shfl_xor(klw, 16, 64);
  klw += __shfl_xor(klw, 32, 64);

  __shared__ float klb[4];
  if (l == 0) klb[w] = klw;
  __syncthreads();
  if (threadIdx.x == 0)
    kl_partial[blockIdx.x * NM + m] = klb[0] + klb[1] + klb[2] + klb[3];
}

// =====================================================================
// encoder: C[s, z*64+h] = A[s,:] . PtE[z*64+h,:]  (MFMA), fused epilogue
// grid (2560/64, 16 z, 5 d), block 256
// =====================================================================
__global__ __launch_bounds__(256) void k_enc_mfma(
    const short* __restrict__ Abf, const short* __restrict__ PtE,
    const float* __restrict__ b0, const float* __restrict__ W1,
    const float* __restrict__ b1, const float* __restrict__ lve,
    float* __restrict__ z_past, float* __restrict__ mu_t, float* __restrict__ z_t)
{
  const int d = blockIdx.z, zb = blockIdx.y;
  const int s0 = blockIdx.x * 64;
  const int w = threadIdx.x >> 6, l = threadIdx.x & 63;
  const int lrow = l & 15, g = l >> 4;

  const int srow = s0 + w * 16 + lrow;
  const short* Arow = Abf + ((size_t)(d * NSAMP + srow)) * NDX + g * 8;
  bf16x8 a[8];
  #pragma unroll
  for (int ks = 0; ks < 8; ++ks) a[ks] = *(const bf16x8*)(Arow + ks * 32);

  f32x4 acc[4] = {};
  #pragma unroll
  for (int nt = 0; nt < 4; ++nt) {
    const short* Brow = PtE + ((size_t)(d * 1024 + zb * 64 + nt * 16 + lrow)) * NDX + g * 8;
    #pragma unroll
    for (int ks = 0; ks < 8; ++ks) {
      bf16x8 b = *(const bf16x8*)(Brow + ks * 32);
      acc[nt] = __builtin_amdgcn_mfma_f32_16x16x32_bf16(a[ks], b, acc[nt], 0, 0, 0);
    }
  }

  float b0v[4], w1v[4];
  #pragma unroll
  for (int nt = 0; nt < 4; ++nt) {
    int h = nt * 16 + lrow;
    b0v[nt] = b0[zb * NH + h];
    w1v[nt] = W1[zb * NH + h];
  }
  float rsum[4];
  #pragma unroll
  for (int reg = 0; reg < 4; ++reg) {
    float v = 0.0f;
    #pragma unroll
    for (int nt = 0; nt < 4; ++nt) {
      float hv = acc[nt][reg] + b0v[nt];
      hv = fmaxf(hv, 0.01f * hv);
      v += hv * w1v[nt];
    }
    #pragma unroll
    for (int off = 1; off < 16; off <<= 1) v += __shfl_xor(v, off, 16);
    rsum[reg] = v;
  }
  if (lrow == 0) {
    float qs = expf(0.5f * lve[d]);
    float b1v = b1[zb];
    #pragma unroll
    for (int reg = 0; reg < 4; ++reg) {
      int s = s0 + w * 16 + g * 4 + reg;
      float mu = rsum[reg] + b1v;
      if (s < NB * NTAU) {
        unsigned long long idx = (unsigned long long)s * NM + d * NDZ + zb;
        float eps = rng_normal(SALT_EP, idx);
        z_past[(size_t)s * NM + d * NDZ + zb] = mu + qs * eps;
      } else {
        int b = s - NB * NTAU;
        unsigned long long idx = (unsigned long long)b * NM + d * NDZ + zb;
        float eps = rng_normal(SALT_ET, idx);
        size_t o = (size_t)b * NM + d * NDZ + zb;
        mu_t[o] = mu;
        z_t[o]  = mu + qs * eps;
      }
    }
  }
}

// =====================================================================
// decoder: hd[b, xx*64+h] = zt[b, d,:16] . QtD  (K=32 padded MFMA), fused recon
// grid (2, 256 xx, 5 d), block 256
// =====================================================================
__global__ __launch_bounds__(256) void k_dec_mfma(
    const float* __restrict__ zt, const short* __restrict__ QtD,
    const float* __restrict__ y, const float* __restrict__ db0,
    const float* __restrict__ dW1, const float* __restrict__ db1,
    const float* __restrict__ lvd, float* __restrict__ rec_partial)
{
  const int d = blockIdx.z, xx = blockIdx.y, mb = blockIdx.x;
  const int w = threadIdx.x >> 6, l = threadIdx.x & 63;
  const int lrow = l & 15, g = l >> 4;

  bf16x8 bfr[4];
  const short* Bbase = QtD + ((size_t)((d * NDX + xx) * NH)) * 32;
  #pragma unroll
  for (int nt = 0; nt < 4; ++nt)
    bfr[nt] = *(const bf16x8*)(Bbase + (nt * 16 + lrow) * 32 + g * 8);

  f32x4 acc[4][4] = {};
  #pragma unroll
  for (int mt = 0; mt < 4; ++mt) {
    int b = mb * 256 + w * 64 + mt * 16 + lrow;
    bf16x8 a = {0, 0, 0, 0, 0, 0, 0, 0};
    if (g < 2) {
      const float* zp = zt + (size_t)b * NM + d * NDZ + g * 8;
      float4 f0 = *(const float4*)zp;
      float4 f1 = *(const float4*)(zp + 4);
      a[0] = f2bf(f0.x); a[1] = f2bf(f0.y); a[2] = f2bf(f0.z); a[3] = f2bf(f0.w);
      a[4] = f2bf(f1.x); a[5] = f2bf(f1.y); a[6] = f2bf(f1.z); a[7] = f2bf(f1.w);
    }
    #pragma unroll
    for (int nt = 0; nt < 4; ++nt)
      acc[mt][nt] = __builtin_amdgcn_mfma_f32_16x16x32_bf16(a, bfr[nt], acc[mt][nt], 0, 0, 0);
  }

  float db0v[4], dW1v[4];
  #pragma unroll
  for (int nt = 0; nt < 4; ++nt) {
    int h = nt * 16 + lrow;
    db0v[nt] = db0[xx * NH + h];
    dW1v[nt] = dW1[xx * NH + h];
  }
  const float lv = lvd[d];
  const float inv_std = expf(-0.5f * lv);
  const float cterm = -0.5f * lv - 0.5f * LOG2PI_F;
  const float b1v = db1[xx];

  float racc = 0.0f;
  #pragma unroll
  for (int mt = 0; mt < 4; ++mt) {
    #pragma unroll
    for (int reg = 0; reg < 4; ++reg) {
      float v = 0.0f;
      #pragma unroll
      for (int nt = 0; nt < 4; ++nt) {
        float hv = acc[mt][nt][reg] + db0v[nt];
        hv = fmaxf(hv, 0.01f * hv);
        v += hv * dW1v[nt];
      }
      #pragma unroll
      for (int off = 1; off < 16; off <<= 1) v += __shfl_xor(v, off, 16);
      if (lrow == 0) {
        int b = mb * 256 + w * 64 + mt * 16 + g * 4 + reg;
        float px = v + b1v;
        float e = (y[((size_t)b * ND + d) * NDX + xx] - px) * inv_std;
        racc += -0.5f * e * e + cterm;
      }
    }
  }
  racc += __shfl_xor(racc, 16, 64);
  racc += __shfl_xor(racc, 32, 64);

  __shared__ float rb[4];
  if (l == 0) rb[w] = racc;
  __syncthreads();
  if (threadIdx.x == 0)
    rec_partial[((size_t)d * NDX + xx) * 2 + mb] = rb[0] + rb[1] + rb[2] + rb[3];
}

// =====================================================================
// K4: final reduction -> loss = (sum_kl - sum_recon) / B
// =====================================================================
__global__ __launch_bounds__(256) void k_reduce(
    const float* __restrict__ rp, const float* __restrict__ kp,
    float* __restrict__ out)
{
  __shared__ float sr[4], sk[4];
  float r = 0.f, k = 0.f;
  for (int i = threadIdx.x; i < 2560; i += 256) r += rp[i];
  for (int i = threadIdx.x; i < 640; i += 256) k += kp[i];
  #pragma unroll
  for (int off = 32; off; off >>= 1) {
    r += __shfl_xor(r, off, 64);
    k += __shfl_xor(k, off, 64);
  }
  int wv = threadIdx.x >> 6;
  if ((threadIdx.x & 63) == 0) { sr[wv] = r; sk[wv] = k; }
  __syncthreads();
  if (threadIdx.x == 0) {
    float R = sr[0] + sr[1] + sr[2] + sr[3];
    float K = sk[0] + sk[1] + sk[2] + sk[3];
    out[0] = (K - R) / (float)NB;
  }
}

// =====================================================================
extern "C" void kernel_launch(void* const* d_in, const int* in_sizes, int n_in,
                              void* d_out, int out_size, void* d_ws, size_t ws_size,
                              hipStream_t stream) {
  (void)in_sizes; (void)n_in; (void)out_size; (void)ws_size;
  const float* x        = (const float*)d_in[0];
  const float* y        = (const float*)d_in[1];
  const float* mask_p   = (const float*)d_in[2];
  const float* w_enc    = (const float*)d_in[3];
  const float* w_dec    = (const float*)d_in[4];
  const float* enc_W0   = (const float*)d_in[5];
  const float* enc_b0   = (const float*)d_in[6];
  const float* enc_W1   = (const float*)d_in[7];
  const float* enc_b1   = (const float*)d_in[8];
  const float* dec_W0   = (const float*)d_in[9];
  const float* dec_b0   = (const float*)d_in[10];
  const float* dec_W1   = (const float*)d_in[11];
  const float* dec_b1   = (const float*)d_in[12];
  const float* t_W0     = (const float*)d_in[13];
  const float* t_b0     = (const float*)d_in[14];
  const float* t_W1     = (const float*)d_in[15];
  const float* t_b1     = (const float*)d_in[16];
  const float* lv_enc   = (const float*)d_in[17];
  const float* lv_dec   = (const float*)d_in[18];
  const float* t_logvar = (const float*)d_in[19];

  float* ws     = (float*)d_ws;
  float* z_past = ws;                         // 163840 f32
  float* mu_t   = z_past + 163840;            // 40960
  float* z_t    = mu_t + 40960;               // 40960
  float* rec_p  = z_t + 40960;                // 2560
  float* kl_p   = rec_p + 2560;               // 640
  float* em     = kl_p + 640;                 // 25600
  short* Abf    = (short*)(em + 25600);       // 5*2560*256
  short* PtE    = Abf + 5 * NSAMP * NDX;      // 5*1024*256
  short* QtD    = PtE + 5 * 1024 * NDX;       // 5*256*64*32
  short* TtB    = QtD + 5 * NDX * NH * 32;    // 80*64*320
  short* gated  = TtB + NM * NH * NTM;        // 80*512*320 (26.2 MB)

  k_prepA<<<5 * NSAMP * NDX / 256, 256, 0, stream>>>(x, y, Abf);
  k_prepP<<<5 * 1024 * NDX / 256, 256, 0, stream>>>(w_enc, enc_W0, PtE);
  k_prepQ<<<5 * NDX * NH / 256, 256, 0, stream>>>(w_dec, dec_W0, QtD);
  k_prepEM<<<NTAU * NM * NM / 256, 256, 0, stream>>>(mask_p, em);
  k_prepT<<<dim3(5, NM), 256, 0, stream>>>(t_W0, TtB);

  k_enc_mfma<<<dim3(NSAMP / 64, NDZ, ND), 256, 0, stream>>>(
      Abf, PtE, enc_b0, enc_W1, enc_b1, lv_enc, z_past, mu_t, z_t);
  k_gated<<<dim3(NB, NM), 320, 0, stream>>>(em, z_past, gated);
  k_trans_mfma<<<dim3(NB / 64, NM), 256, 0, stream>>>(
      gated, TtB, t_b0, t_W1, t_b1, lv_enc, t_logvar, mu_t, kl_p);
  k_dec_mfma<<<dim3(2, NDX, ND), 256, 0, stream>>>(
      z_t, QtD, y, dec_b0, dec_W1, dec_b1, lv_dec, rec_p);
  k_reduce<<<1, 256, 0, stream>>>(rec_p, kl_p, (float*)d_out);
}

// Round 4
// 167.673 us; speedup vs baseline: 3.8399x; 1.0020x over previous
//
#include <hip/hip_runtime.h>
#include <cstdint>

// ---- problem dims ----
constexpr int NB = 512, NTAU = 4, ND = 5, NDX = 256, NDZ = 16, NH = 64;
constexpr int NM  = ND * NDZ;          // 80
constexpr int NTM = NTAU * NM;         // 320
constexpr int NSAMP = NB * NTAU + NB;  // 2560 (past samples then t samples)
constexpr float LOG2PI_F = 1.8378770664093453f;

typedef __attribute__((ext_vector_type(8))) short bf16x8;
typedef __attribute__((ext_vector_type(4))) float f32x4;

// ---- counter-based RNG (distribution-exact stand-in for jax.random) ----
__device__ __forceinline__ unsigned long long mix64(unsigned long long z) {
  z += 0x9E3779B97F4A7C15ull;
  z = (z ^ (z >> 30)) * 0xBF58476D1CE4E5B9ull;
  z = (z ^ (z >> 27)) * 0x94D049BB133111EBull;
  return z ^ (z >> 31);
}
__device__ __forceinline__ float u01f(unsigned long long h) {
  return ((float)(unsigned)(h >> 40) + 0.5f) * (1.0f / 16777216.0f);
}
__device__ __forceinline__ float rng_normal(unsigned long long salt, unsigned long long idx) {
  float u1 = u01f(mix64(salt + 2ull * idx));
  float u2 = u01f(mix64(salt + 2ull * idx + 1ull));
  float r = sqrtf(-2.0f * logf(u1));
  return r * cosf(6.283185307179586f * u2);
}
constexpr unsigned long long SALT_ADJ = 0x1000000000000ull;
constexpr unsigned long long SALT_EP  = 0x2000000000000ull;
constexpr unsigned long long SALT_ET  = 0x3000000000000ull;

__device__ __forceinline__ short f2bf(float f) {
  unsigned u = __float_as_uint(f);
  unsigned r = (u + 0x7FFFu + ((u >> 16) & 1u)) >> 16;
  return (short)r;
}

// =====================================================================
// prep kernels: bf16 operand materialization
// =====================================================================
__global__ __launch_bounds__(256) void k_prepA(
    const float* __restrict__ x, const float* __restrict__ y, short* __restrict__ Abf)
{
  int idx = blockIdx.x * 256 + threadIdx.x;
  int d = idx / (NSAMP * NDX);
  int r = idx % (NSAMP * NDX);
  int s = r >> 8, xx = r & 255;
  float v = (s < NB * NTAU) ? x[((size_t)s * ND + d) * NDX + xx]
                            : y[((size_t)(s - NB * NTAU) * ND + d) * NDX + xx];
  Abf[idx] = f2bf(v);
}

__global__ __launch_bounds__(256) void k_prepP(
    const float* __restrict__ w_enc, const float* __restrict__ W0, short* __restrict__ PtE)
{
  int idx = blockIdx.x * 256 + threadIdx.x;
  int d = idx / (1024 * NDX);
  int r = idx % (1024 * NDX);
  int col = r >> 8, xx = r & 255;
  int z = col >> 6, h = col & 63;
  float v = w_enc[((size_t)d * NDZ + z) * NDX + xx] * W0[((size_t)z * NDX + xx) * NH + h];
  PtE[idx] = f2bf(v);
}

__global__ __launch_bounds__(256) void k_prepQ(
    const float* __restrict__ w_dec, const float* __restrict__ dW0, short* __restrict__ QtD)
{
  int t = blockIdx.x * 256 + threadIdx.x;
  int d = t / (NDX * NH);
  int r = t % (NDX * NH);
  int xx = r >> 6, h = r & 63;
  size_t base = (size_t)t * 32;
  #pragma unroll
  for (int z = 0; z < NDZ; ++z)
    QtD[base + z] = f2bf(w_dec[((size_t)d * NDX + xx) * NDZ + z] *
                         dW0[((size_t)xx * NDZ + z) * NH + h]);
  #pragma unroll
  for (int z = NDZ; z < 32; ++z) QtD[base + z] = 0;
}

// EM[t][m][s] = exp(-mask_param[t][m][s])
__global__ __launch_bounds__(256) void k_prepEM(
    const float* __restrict__ mask_param, float* __restrict__ em)
{
  int idx = blockIdx.x * 256 + threadIdx.x;
  em[idx] = expf(-mask_param[idx]);
}

// TtB[m][h][k] = bf16(t_W0[m][k][h])  via LDS transpose
__global__ __launch_bounds__(256) void k_prepT(
    const float* __restrict__ tW0, short* __restrict__ TtB)
{
  __shared__ short lds[64][65];
  const int m = blockIdx.y, k0 = blockIdx.x * 64;
  for (int idx = threadIdx.x; idx < 64 * 64; idx += 256) {
    int hh = idx & 63, kk = idx >> 6;
    lds[kk][hh] = f2bf(tW0[((size_t)m * NTM + k0 + kk) * NH + hh]);
  }
  __syncthreads();
  for (int idx = threadIdx.x; idx < 64 * 64; idx += 256) {
    int kk = idx & 63, hh = idx >> 6;
    TtB[((size_t)m * NH + hh) * NTM + k0 + kk] = lds[kk][hh];
  }
}

// =====================================================================
// encoder GEMM: mu_all[s][m=d*16+z] = leaky-MLP head over MFMA tiles
// grid (2560/64, 2 z-halves, 5 d), block 256 (4 waves x 16 rows)
// A fragments resident across the 8-z loop; no RNG in epilogue.
// =====================================================================
__global__ __launch_bounds__(256) void k_enc_mfma(
    const short* __restrict__ Abf, const short* __restrict__ PtE,
    const float* __restrict__ b0, const float* __restrict__ W1,
    const float* __restrict__ b1, float* __restrict__ mu_all)
{
  const int d = blockIdx.z, zh = blockIdx.y;
  const int s0 = blockIdx.x * 64;
  const int w = threadIdx.x >> 6, l = threadIdx.x & 63;
  const int lrow = l & 15, g = l >> 4;

  const int srow = s0 + w * 16 + lrow;
  const short* Arow = Abf + ((size_t)(d * NSAMP + srow)) * NDX + g * 8;
  bf16x8 a[8];
  #pragma unroll
  for (int ks = 0; ks < 8; ++ks) a[ks] = *(const bf16x8*)(Arow + ks * 32);

  for (int zi = 0; zi < 8; ++zi) {
    const int z = zh * 8 + zi;
    f32x4 acc[4] = {};
    #pragma unroll
    for (int nt = 0; nt < 4; ++nt) {
      const short* Brow = PtE + ((size_t)(d * 1024 + z * 64 + nt * 16 + lrow)) * NDX + g * 8;
      #pragma unroll
      for (int ks = 0; ks < 8; ++ks) {
        bf16x8 bv = *(const bf16x8*)(Brow + ks * 32);
        acc[nt] = __builtin_amdgcn_mfma_f32_16x16x32_bf16(a[ks], bv, acc[nt], 0, 0, 0);
      }
    }
    float b0v[4], w1v[4];
    #pragma unroll
    for (int nt = 0; nt < 4; ++nt) {
      int h = nt * 16 + lrow;
      b0v[nt] = b0[z * NH + h];
      w1v[nt] = W1[z * NH + h];
    }
    const float b1v = b1[z];
    #pragma unroll
    for (int reg = 0; reg < 4; ++reg) {
      float v = 0.0f;
      #pragma unroll
      for (int nt = 0; nt < 4; ++nt) {
        float hv = acc[nt][reg] + b0v[nt];
        hv = fmaxf(hv, 0.01f * hv);
        v += hv * w1v[nt];
      }
      #pragma unroll
      for (int off = 1; off < 16; off <<= 1) v += __shfl_xor(v, off, 16);
      if (lrow == 0) {
        int s = s0 + w * 16 + g * 4 + reg;
        mu_all[(size_t)s * NM + d * NDZ + z] = v + b1v;
      }
    }
  }
}

// =====================================================================
// reparameterization: one thread per (s, m) element
// grid (2560*80/256), block 256
// =====================================================================
__global__ __launch_bounds__(256) void k_noise(
    const float* __restrict__ mu_all, const float* __restrict__ lve,
    float* __restrict__ z_past, float* __restrict__ mu_t, float* __restrict__ z_t)
{
  int i = blockIdx.x * 256 + threadIdx.x;   // < 2560*80
  int s = i / NM, m = i - s * NM;
  int d = m >> 4;
  float mu = mu_all[i];
  float qs = expf(0.5f * lve[d]);
  if (s < NB * NTAU) {
    float eps = rng_normal(SALT_EP, (unsigned long long)s * NM + m);
    z_past[i] = mu + qs * eps;
  } else {
    int b = s - NB * NTAU;
    float eps = rng_normal(SALT_ET, (unsigned long long)b * NM + m);
    size_t o = (size_t)b * NM + m;
    mu_t[o] = mu;
    z_t[o]  = mu + qs * eps;
  }
}

// =====================================================================
// gated[m][b][tm] = bf16( adj(b,t,m,s) * z_past[b][tm] )
// grid (NB, NM), block 320
// =====================================================================
__global__ __launch_bounds__(320) void k_gated(
    const float* __restrict__ em, const float* __restrict__ z_past,
    short* __restrict__ gated)
{
  const int b = blockIdx.x, m = blockIdx.y;
  const int tm = threadIdx.x;
  const int t = tm / NM, s = tm - t * NM;
  unsigned long long ai = ((unsigned long long)((b * NTAU + t) * NM + m)) * NM + s;
  float u = u01f(mix64(SALT_ADJ + ai));
  u = fminf(fmaxf(u, 1e-6f), 1.0f - 1e-6f);
  float e = em[(t * NM + m) * NM + s];
  float adj = u / (u + e * (1.0f - u));
  float zp = z_past[(size_t)b * NTM + tm];
  gated[((size_t)m * NB + b) * NTM + tm] = f2bf(adj * zp);
}

// =====================================================================
// transition GEMM + KL (MFMA over K=320), fused KL partial sums
// grid (NB/64, NM), block 256
// =====================================================================
__global__ __launch_bounds__(256) void k_trans_mfma(
    const short* __restrict__ gated, const short* __restrict__ TtB,
    const float* __restrict__ tb0, const float* __restrict__ tW1,
    const float* __restrict__ tb1, const float* __restrict__ lve,
    const float* __restrict__ t_logvar, const float* __restrict__ mu_t,
    float* __restrict__ kl_partial)
{
  const int m = blockIdx.y;
  const int b0 = blockIdx.x * 64;
  const int w = threadIdx.x >> 6, l = threadIdx.x & 63;
  const int lrow = l & 15, g = l >> 4;

  const short* Arow = gated + ((size_t)(m * NB + b0 + w * 16 + lrow)) * NTM + g * 8;
  bf16x8 a[10];
  #pragma unroll
  for (int ks = 0; ks < 10; ++ks) a[ks] = *(const bf16x8*)(Arow + ks * 32);

  f32x4 acc[4] = {};
  #pragma unroll
  for (int nt = 0; nt < 4; ++nt) {
    const short* Brow = TtB + ((size_t)(m * NH + nt * 16 + lrow)) * NTM + g * 8;
    #pragma unroll
    for (int ks = 0; ks < 10; ++ks) {
      bf16x8 bv = *(const bf16x8*)(Brow + ks * 32);
      acc[nt] = __builtin_amdgcn_mfma_f32_16x16x32_bf16(a[ks], bv, acc[nt], 0, 0, 0);
    }
  }

  float b0v[4], w1v[4];
  #pragma unroll
  for (int nt = 0; nt < 4; ++nt) {
    int h = nt * 16 + lrow;
    b0v[nt] = tb0[m * NH + h];
    w1v[nt] = tW1[m * NH + h];
  }

  const int d = m >> 4;
  const float lv_t = t_logvar[m];
  const float lv_e = lve[d];
  const float inv2var = 0.5f * expf(-lv_t);
  const float qvar = expf(lv_e);
  const float cterm = 0.5f * lv_t - 0.5f * lv_e - 0.5f;
  const float bv1 = tb1[m];

  float klw = 0.0f;
  #pragma unroll
  for (int reg = 0; reg < 4; ++reg) {
    float v = 0.0f;
    #pragma unroll
    for (int nt = 0; nt < 4; ++nt) {
      float hv = acc[nt][reg] + b0v[nt];
      hv = fmaxf(hv, 0.01f * hv);
      v += hv * w1v[nt];
    }
    #pragma unroll
    for (int off = 1; off < 16; off <<= 1) v += __shfl_xor(v, off, 16);
    if (lrow == 0) {
      int b = b0 + w * 16 + g * 4 + reg;
      float pz = v + bv1;
      float diff = mu_t[(size_t)b * NM + m] - pz;
      klw += cterm + (qvar + diff * diff) * inv2var;
    }
  }
  klw += __shfl_xor(klw, 16, 64);
  klw += __shfl_xor(klw, 32, 64);

  __shared__ float klb[4];
  if (l == 0) klb[w] = klw;
  __syncthreads();
  if (threadIdx.x == 0)
    kl_partial[blockIdx.x * NM + m] = klb[0] + klb[1] + klb[2] + klb[3];
}

// =====================================================================
// decoder: K=32 padded MFMA, fused recon partial sums
// grid (2, 256 xx, 5 d), block 256
// =====================================================================
__global__ __launch_bounds__(256) void k_dec_mfma(
    const float* __restrict__ zt, const short* __restrict__ QtD,
    const float* __restrict__ y, const float* __restrict__ db0,
    const float* __restrict__ dW1, const float* __restrict__ db1,
    const float* __restrict__ lvd, float* __restrict__ rec_partial)
{
  const int d = blockIdx.z, xx = blockIdx.y, mb = blockIdx.x;
  const int w = threadIdx.x >> 6, l = threadIdx.x & 63;
  const int lrow = l & 15, g = l >> 4;

  bf16x8 bfr[4];
  const short* Bbase = QtD + ((size_t)((d * NDX + xx) * NH)) * 32;
  #pragma unroll
  for (int nt = 0; nt < 4; ++nt)
    bfr[nt] = *(const bf16x8*)(Bbase + (nt * 16 + lrow) * 32 + g * 8);

  f32x4 acc[4][4] = {};
  #pragma unroll
  for (int mt = 0; mt < 4; ++mt) {
    int b = mb * 256 + w * 64 + mt * 16 + lrow;
    bf16x8 a = {0, 0, 0, 0, 0, 0, 0, 0};
    if (g < 2) {
      const float* zp = zt + (size_t)b * NM + d * NDZ + g * 8;
      float4 f0 = *(const float4*)zp;
      float4 f1 = *(const float4*)(zp + 4);
      a[0] = f2bf(f0.x); a[1] = f2bf(f0.y); a[2] = f2bf(f0.z); a[3] = f2bf(f0.w);
      a[4] = f2bf(f1.x); a[5] = f2bf(f1.y); a[6] = f2bf(f1.z); a[7] = f2bf(f1.w);
    }
    #pragma unroll
    for (int nt = 0; nt < 4; ++nt)
      acc[mt][nt] = __builtin_amdgcn_mfma_f32_16x16x32_bf16(a, bfr[nt], acc[mt][nt], 0, 0, 0);
  }

  float db0v[4], dW1v[4];
  #pragma unroll
  for (int nt = 0; nt < 4; ++nt) {
    int h = nt * 16 + lrow;
    db0v[nt] = db0[xx * NH + h];
    dW1v[nt] = dW1[xx * NH + h];
  }
  const float lv = lvd[d];
  const float inv_std = expf(-0.5f * lv);
  const float cterm = -0.5f * lv - 0.5f * LOG2PI_F;
  const float b1v = db1[xx];

  float racc = 0.0f;
  #pragma unroll
  for (int mt = 0; mt < 4; ++mt) {
    #pragma unroll
    for (int reg = 0; reg < 4; ++reg) {
      float v = 0.0f;
      #pragma unroll
      for (int nt = 0; nt < 4; ++nt) {
        float hv = acc[mt][nt][reg] + db0v[nt];
        hv = fmaxf(hv, 0.01f * hv);
        v += hv * dW1v[nt];
      }
      #pragma unroll
      for (int off = 1; off < 16; off <<= 1) v += __shfl_xor(v, off, 16);
      if (lrow == 0) {
        int b = mb * 256 + w * 64 + mt * 16 + g * 4 + reg;
        float px = v + b1v;
        float e = (y[((size_t)b * ND + d) * NDX + xx] - px) * inv_std;
        racc += -0.5f * e * e + cterm;
      }
    }
  }
  racc += __shfl_xor(racc, 16, 64);
  racc += __shfl_xor(racc, 32, 64);

  __shared__ float rb[4];
  if (l == 0) rb[w] = racc;
  __syncthreads();
  if (threadIdx.x == 0)
    rec_partial[((size_t)d * NDX + xx) * 2 + mb] = rb[0] + rb[1] + rb[2] + rb[3];
}

// =====================================================================
// final reduction -> loss = (sum_kl - sum_recon) / B
// =====================================================================
__global__ __launch_bounds__(256) void k_reduce(
    const float* __restrict__ rp, const float* __restrict__ kp,
    float* __restrict__ out)
{
  __shared__ float sr[4], sk[4];
  float r = 0.f, k = 0.f;
  for (int i = threadIdx.x; i < 2560; i += 256) r += rp[i];
  for (int i = threadIdx.x; i < 640; i += 256) k += kp[i];
  #pragma unroll
  for (int off = 32; off; off >>= 1) {
    r += __shfl_xor(r, off, 64);
    k += __shfl_xor(k, off, 64);
  }
  int wv = threadIdx.x >> 6;
  if ((threadIdx.x & 63) == 0) { sr[wv] = r; sk[wv] = k; }
  __syncthreads();
  if (threadIdx.x == 0) {
    float R = sr[0] + sr[1] + sr[2] + sr[3];
    float K = sk[0] + sk[1] + sk[2] + sk[3];
    out[0] = (K - R) / (float)NB;
  }
}

// =====================================================================
extern "C" void kernel_launch(void* const* d_in, const int* in_sizes, int n_in,
                              void* d_out, int out_size, void* d_ws, size_t ws_size,
                              hipStream_t stream) {
  (void)in_sizes; (void)n_in; (void)out_size; (void)ws_size;
  const float* x        = (const float*)d_in[0];
  const float* y        = (const float*)d_in[1];
  const float* mask_p   = (const float*)d_in[2];
  const float* w_enc    = (const float*)d_in[3];
  const float* w_dec    = (const float*)d_in[4];
  const float* enc_W0   = (const float*)d_in[5];
  const float* enc_b0   = (const float*)d_in[6];
  const float* enc_W1   = (const float*)d_in[7];
  const float* enc_b1   = (const float*)d_in[8];
  const float* dec_W0   = (const float*)d_in[9];
  const float* dec_b0   = (const float*)d_in[10];
  const float* dec_W1   = (const float*)d_in[11];
  const float* dec_b1   = (const float*)d_in[12];
  const float* t_W0     = (const float*)d_in[13];
  const float* t_b0     = (const float*)d_in[14];
  const float* t_W1     = (const float*)d_in[15];
  const float* t_b1     = (const float*)d_in[16];
  const float* lv_enc   = (const float*)d_in[17];
  const float* lv_dec   = (const float*)d_in[18];
  const float* t_logvar = (const float*)d_in[19];

  float* ws     = (float*)d_ws;
  float* z_past = ws;                         // 163840 f32
  float* mu_t   = z_past + 163840;            // 40960
  float* z_t    = mu_t + 40960;               // 40960
  float* rec_p  = z_t + 40960;                // 2560
  float* kl_p   = rec_p + 2560;               // 640
  float* em     = kl_p + 640;                 // 25600
  float* mu_all = em + 25600;                 // 204800
  short* Abf    = (short*)(mu_all + 204800);  // 5*2560*256
  short* PtE    = Abf + 5 * NSAMP * NDX;      // 5*1024*256
  short* QtD    = PtE + 5 * 1024 * NDX;       // 5*256*64*32
  short* TtB    = QtD + 5 * NDX * NH * 32;    // 80*64*320
  short* gated  = TtB + NM * NH * NTM;        // 80*512*320 (26.2 MB)

  k_prepA<<<5 * NSAMP * NDX / 256, 256, 0, stream>>>(x, y, Abf);
  k_prepP<<<5 * 1024 * NDX / 256, 256, 0, stream>>>(w_enc, enc_W0, PtE);
  k_prepQ<<<5 * NDX * NH / 256, 256, 0, stream>>>(w_dec, dec_W0, QtD);
  k_prepEM<<<NTAU * NM * NM / 256, 256, 0, stream>>>(mask_p, em);
  k_prepT<<<dim3(5, NM), 256, 0, stream>>>(t_W0, TtB);

  k_enc_mfma<<<dim3(NSAMP / 64, 2, ND), 256, 0, stream>>>(
      Abf, PtE, enc_b0, enc_W1, enc_b1, mu_all);
  k_noise<<<NSAMP * NM / 256, 256, 0, stream>>>(mu_all, lv_enc, z_past, mu_t, z_t);
  k_gated<<<dim3(NB, NM), 320, 0, stream>>>(em, z_past, gated);
  k_trans_mfma<<<dim3(NB / 64, NM), 256, 0, stream>>>(
      gated, TtB, t_b0, t_W1, t_b1, lv_enc, t_logvar, mu_t, kl_p);
  k_dec_mfma<<<dim3(2, NDX, ND), 256, 0, stream>>>(
      z_t, QtD, y, dec_b0, dec_W1, dec_b1, lv_dec, rec_p);
  k_reduce<<<1, 256, 0, stream>>>(rec_p, kl_p, (float*)d_out);
}

// Round 5
// 123.235 us; speedup vs baseline: 5.2245x; 1.3606x over previous
//
#include <hip/hip_runtime.h>
#include <cstdint>

// ---- problem dims ----
constexpr int NB = 512, NTAU = 4, ND = 5, NDX = 256, NDZ = 16, NH = 64;
constexpr int NM  = ND * NDZ;          // 80
constexpr int NTM = NTAU * NM;         // 320
constexpr int NSAMP = NB * NTAU + NB;  // 2560 (past samples then t samples)
constexpr float LOG2PI_F = 1.8378770664093453f;

typedef __attribute__((ext_vector_type(8))) short bf16x8;
typedef __attribute__((ext_vector_type(4))) float f32x4;

// ---- counter-based RNG (distribution-exact stand-in for jax.random) ----
__device__ __forceinline__ unsigned long long mix64(unsigned long long z) {
  z += 0x9E3779B97F4A7C15ull;
  z = (z ^ (z >> 30)) * 0xBF58476D1CE4E5B9ull;
  z = (z ^ (z >> 27)) * 0x94D049BB133111EBull;
  return z ^ (z >> 31);
}
__device__ __forceinline__ float u01f(unsigned long long h) {
  return ((float)(unsigned)(h >> 40) + 0.5f) * (1.0f / 16777216.0f);
}
__device__ __forceinline__ float rng_normal(unsigned long long salt, unsigned long long idx) {
  float u1 = u01f(mix64(salt + 2ull * idx));
  float u2 = u01f(mix64(salt + 2ull * idx + 1ull));
  float r = sqrtf(-2.0f * logf(u1));
  return r * cosf(6.283185307179586f * u2);
}
constexpr unsigned long long SALT_ADJ = 0x1000000000000ull;
constexpr unsigned long long SALT_EP  = 0x2000000000000ull;
constexpr unsigned long long SALT_ET  = 0x3000000000000ull;

__device__ __forceinline__ short f2bf(float f) {
  unsigned u = __float_as_uint(f);
  unsigned r = (u + 0x7FFFu + ((u >> 16) & 1u)) >> 16;
  return (short)r;
}

// =====================================================================
// k_prepW: all bf16 operand materialization, one launch.
// block ranges: [0,12800) A, [12800,17920) P, [17920,18240) Q,
//               [18240,18340) EM, [18340,18740) T
// =====================================================================
__global__ __launch_bounds__(256) void k_prepW(
    const float* __restrict__ x, const float* __restrict__ y, short* __restrict__ Abf,
    const float* __restrict__ w_enc, const float* __restrict__ eW0, short* __restrict__ PtE,
    const float* __restrict__ w_dec, const float* __restrict__ dW0, short* __restrict__ QtD,
    const float* __restrict__ mask_param, float* __restrict__ em,
    const float* __restrict__ tW0, short* __restrict__ TtB)
{
  __shared__ short lds[64][65];
  const int bid = blockIdx.x;
  if (bid < 12800) {
    // Abf[d][s][xx]
    int idx = bid * 256 + threadIdx.x;
    int d = idx / (NSAMP * NDX);
    int r = idx % (NSAMP * NDX);
    int s = r >> 8, xx = r & 255;
    float v = (s < NB * NTAU) ? x[((size_t)s * ND + d) * NDX + xx]
                              : y[((size_t)(s - NB * NTAU) * ND + d) * NDX + xx];
    Abf[idx] = f2bf(v);
  } else if (bid < 17920) {
    // PtE[d][col=z*64+h][xx] = w_enc[d,z,xx] * eW0[z,xx,h]
    int idx = (bid - 12800) * 256 + threadIdx.x;
    int d = idx / (1024 * NDX);
    int r = idx % (1024 * NDX);
    int col = r >> 8, xx = r & 255;
    int z = col >> 6, h = col & 63;
    float v = w_enc[((size_t)d * NDZ + z) * NDX + xx] * eW0[((size_t)z * NDX + xx) * NH + h];
    PtE[idx] = f2bf(v);
  } else if (bid < 18240) {
    // QtD[((d*256+xx)*64+h)][k<32]
    int t = (bid - 17920) * 256 + threadIdx.x;
    int d = t / (NDX * NH);
    int r = t % (NDX * NH);
    int xx = r >> 6, h = r & 63;
    size_t base = (size_t)t * 32;
    #pragma unroll
    for (int z = 0; z < NDZ; ++z)
      QtD[base + z] = f2bf(w_dec[((size_t)d * NDX + xx) * NDZ + z] *
                           dW0[((size_t)xx * NDZ + z) * NH + h]);
    #pragma unroll
    for (int z = NDZ; z < 32; ++z) QtD[base + z] = 0;
  } else if (bid < 18340) {
    int idx = (bid - 18240) * 256 + threadIdx.x;
    em[idx] = expf(-mask_param[idx]);
  } else {
    // TtB[m][h][k] = bf16(tW0[m][k][h]) via LDS transpose; r -> (kt, m)
    int r = bid - 18340;
    int kt = r % 5, m = r / 5;
    int k0 = kt * 64;
    for (int idx = threadIdx.x; idx < 64 * 64; idx += 256) {
      int hh = idx & 63, kk = idx >> 6;
      lds[kk][hh] = f2bf(tW0[((size_t)m * NTM + k0 + kk) * NH + hh]);
    }
    __syncthreads();
    for (int idx = threadIdx.x; idx < 64 * 64; idx += 256) {
      int kk = idx & 63, hh = idx >> 6;
      TtB[((size_t)m * NH + hh) * NTM + k0 + kk] = lds[kk][hh];
    }
  }
}

// =====================================================================
// encoder GEMM v3: LDS-shared B per z, A resident, 4-z loop
// grid (40 sb, 4 zq, 5 d), block 256 (4 waves x 16 s-rows)
// =====================================================================
__global__ __launch_bounds__(256) void k_enc_mfma(
    const short* __restrict__ Abf, const short* __restrict__ PtE,
    const float* __restrict__ b0, const float* __restrict__ W1,
    const float* __restrict__ b1, float* __restrict__ mu_all)
{
  __shared__ __align__(16) short Bs[64 * 264];   // pad 264: bank-uniform b128 reads

  const int d = blockIdx.z, zq = blockIdx.y;
  const int s0 = blockIdx.x * 64;
  const int tid = threadIdx.x;
  const int w = tid >> 6, l = tid & 63;
  const int lrow = l & 15, g = l >> 4;

  // A fragments resident across the z loop (wave w owns rows s0+w*16..+15)
  const short* Arow = Abf + ((size_t)(d * NSAMP + s0 + w * 16 + lrow)) * NDX + g * 8;
  bf16x8 a[8];
  #pragma unroll
  for (int ks = 0; ks < 8; ++ks) a[ks] = *(const bf16x8*)(Arow + ks * 32);

  const int stg_row = tid >> 2;     // 0..63 (B column within z-group)
  const int stg_cg  = tid & 3;      // 64-short chunk of K

  for (int zi = 0; zi < 4; ++zi) {
    const int z = zq * 4 + zi;
    // stage B chunk: PtE[d][z*64 + c][k] -> Bs[c*264 + k]
    {
      const short* src = PtE + ((size_t)(d * 1024 + z * 64 + stg_row)) * NDX + stg_cg * 64;
      short* dst = Bs + stg_row * 264 + stg_cg * 64;
      #pragma unroll
      for (int j = 0; j < 8; ++j)
        *(bf16x8*)(dst + j * 8) = *(const bf16x8*)(src + j * 8);
    }
    __syncthreads();

    f32x4 acc[4] = {};
    #pragma unroll
    for (int nt = 0; nt < 4; ++nt) {
      const short* Brow = Bs + (nt * 16 + lrow) * 264 + g * 8;
      #pragma unroll
      for (int ks = 0; ks < 8; ++ks) {
        bf16x8 bv = *(const bf16x8*)(Brow + ks * 32);
        acc[nt] = __builtin_amdgcn_mfma_f32_16x16x32_bf16(a[ks], bv, acc[nt], 0, 0, 0);
      }
    }

    float b0v[4], w1v[4];
    #pragma unroll
    for (int nt = 0; nt < 4; ++nt) {
      int h = nt * 16 + lrow;
      b0v[nt] = b0[z * NH + h];
      w1v[nt] = W1[z * NH + h];
    }
    const float b1v = b1[z];
    #pragma unroll
    for (int reg = 0; reg < 4; ++reg) {
      float v = 0.0f;
      #pragma unroll
      for (int nt = 0; nt < 4; ++nt) {
        float hv = acc[nt][reg] + b0v[nt];
        hv = fmaxf(hv, 0.01f * hv);
        v += hv * w1v[nt];
      }
      #pragma unroll
      for (int off = 1; off < 16; off <<= 1) v += __shfl_xor(v, off, 16);
      if (lrow == 0) {
        int s = s0 + w * 16 + g * 4 + reg;
        mu_all[(size_t)s * NM + d * NDZ + z] = v + b1v;
      }
    }
    __syncthreads();
  }
}

// =====================================================================
// reparameterization: one thread per (s, m) element
// =====================================================================
__global__ __launch_bounds__(256) void k_noise(
    const float* __restrict__ mu_all, const float* __restrict__ lve,
    float* __restrict__ z_past, float* __restrict__ mu_t, float* __restrict__ z_t)
{
  int i = blockIdx.x * 256 + threadIdx.x;   // < 2560*80
  int s = i / NM, m = i - s * NM;
  int d = m >> 4;
  float mu = mu_all[i];
  float qs = expf(0.5f * lve[d]);
  if (s < NB * NTAU) {
    float eps = rng_normal(SALT_EP, (unsigned long long)s * NM + m);
    z_past[i] = mu + qs * eps;
  } else {
    int b = s - NB * NTAU;
    float eps = rng_normal(SALT_ET, (unsigned long long)b * NM + m);
    size_t o = (size_t)b * NM + m;
    mu_t[o] = mu;
    z_t[o]  = mu + qs * eps;
  }
}

// =====================================================================
// transition: fused gating (LDS) + MFMA over K=320 + analytic KL
// grid (8 bq, 80 m), block 256
// =====================================================================
__global__ __launch_bounds__(256) void k_trans_mfma(
    const float* __restrict__ em, const float* __restrict__ z_past,
    const short* __restrict__ TtB,
    const float* __restrict__ tb0, const float* __restrict__ tW1,
    const float* __restrict__ tb1, const float* __restrict__ lve,
    const float* __restrict__ t_logvar, const float* __restrict__ mu_t,
    float* __restrict__ kl_partial)
{
  __shared__ __align__(16) short gl[64 * 328];   // pad 328: bank-uniform b128 reads
  __shared__ float emv[NTM];
  __shared__ float klb[4];

  const int m   = blockIdx.y;
  const int b0i = blockIdx.x * 64;
  const int tid = threadIdx.x;

  for (int i = tid; i < NTM; i += 256) {
    int t = i / NM, s = i - t * NM;
    emv[i] = em[(t * NM + m) * NM + s];
  }
  __syncthreads();

  // gated[bl][tm] = bf16( adj * z_past[b][tm] ), adj via folded gumbel-sigmoid
  for (int idx = tid; idx < 64 * NTM; idx += 256) {
    int bl = idx / NTM, tm = idx - bl * NTM;
    int t = tm / NM, s = tm - t * NM;
    int b = b0i + bl;
    unsigned long long ai = ((unsigned long long)((b * NTAU + t) * NM + m)) * NM + s;
    float u = u01f(mix64(SALT_ADJ + ai));
    u = fminf(fmaxf(u, 1e-6f), 1.0f - 1e-6f);
    float e = emv[tm];
    float adj = u / (u + e * (1.0f - u));
    float zp = z_past[(size_t)b * NTM + tm];
    gl[bl * 328 + tm] = f2bf(adj * zp);
  }
  __syncthreads();

  const int w = tid >> 6, l = tid & 63;
  const int lrow = l & 15, g = l >> 4;

  const short* Arow = gl + (w * 16 + lrow) * 328 + g * 8;
  bf16x8 a[10];
  #pragma unroll
  for (int ks = 0; ks < 10; ++ks) a[ks] = *(const bf16x8*)(Arow + ks * 32);

  f32x4 acc[4] = {};
  #pragma unroll
  for (int nt = 0; nt < 4; ++nt) {
    const short* Brow = TtB + ((size_t)(m * NH + nt * 16 + lrow)) * NTM + g * 8;
    #pragma unroll
    for (int ks = 0; ks < 10; ++ks) {
      bf16x8 bv = *(const bf16x8*)(Brow + ks * 32);
      acc[nt] = __builtin_amdgcn_mfma_f32_16x16x32_bf16(a[ks], bv, acc[nt], 0, 0, 0);
    }
  }

  float b0v[4], w1v[4];
  #pragma unroll
  for (int nt = 0; nt < 4; ++nt) {
    int h = nt * 16 + lrow;
    b0v[nt] = tb0[m * NH + h];
    w1v[nt] = tW1[m * NH + h];
  }

  const int d = m >> 4;
  const float lv_t = t_logvar[m];
  const float lv_e = lve[d];
  const float inv2var = 0.5f * expf(-lv_t);
  const float qvar = expf(lv_e);
  const float cterm = 0.5f * lv_t - 0.5f * lv_e - 0.5f;
  const float bv1 = tb1[m];

  float klw = 0.0f;
  #pragma unroll
  for (int reg = 0; reg < 4; ++reg) {
    float v = 0.0f;
    #pragma unroll
    for (int nt = 0; nt < 4; ++nt) {
      float hv = acc[nt][reg] + b0v[nt];
      hv = fmaxf(hv, 0.01f * hv);
      v += hv * w1v[nt];
    }
    #pragma unroll
    for (int off = 1; off < 16; off <<= 1) v += __shfl_xor(v, off, 16);
    if (lrow == 0) {
      int b = b0i + w * 16 + g * 4 + reg;
      float pz = v + bv1;
      float diff = mu_t[(size_t)b * NM + m] - pz;
      klw += cterm + (qvar + diff * diff) * inv2var;
    }
  }
  klw += __shfl_xor(klw, 16, 64);
  klw += __shfl_xor(klw, 32, 64);

  if (l == 0) klb[w] = klw;
  __syncthreads();
  if (tid == 0)
    kl_partial[blockIdx.x * NM + m] = klb[0] + klb[1] + klb[2] + klb[3];
}

// =====================================================================
// decoder: K=32 padded MFMA, fused recon partial sums
// grid (2, 256 xx, 5 d), block 256
// =====================================================================
__global__ __launch_bounds__(256) void k_dec_mfma(
    const float* __restrict__ zt, const short* __restrict__ QtD,
    const float* __restrict__ y, const float* __restrict__ db0,
    const float* __restrict__ dW1, const float* __restrict__ db1,
    const float* __restrict__ lvd, float* __restrict__ rec_partial)
{
  const int d = blockIdx.z, xx = blockIdx.y, mb = blockIdx.x;
  const int w = threadIdx.x >> 6, l = threadIdx.x & 63;
  const int lrow = l & 15, g = l >> 4;

  bf16x8 bfr[4];
  const short* Bbase = QtD + ((size_t)((d * NDX + xx) * NH)) * 32;
  #pragma unroll
  for (int nt = 0; nt < 4; ++nt)
    bfr[nt] = *(const bf16x8*)(Bbase + (nt * 16 + lrow) * 32 + g * 8);

  f32x4 acc[4][4] = {};
  #pragma unroll
  for (int mt = 0; mt < 4; ++mt) {
    int b = mb * 256 + w * 64 + mt * 16 + lrow;
    bf16x8 a = {0, 0, 0, 0, 0, 0, 0, 0};
    if (g < 2) {
      const float* zp = zt + (size_t)b * NM + d * NDZ + g * 8;
      float4 f0 = *(const float4*)zp;
      float4 f1 = *(const float4*)(zp + 4);
      a[0] = f2bf(f0.x); a[1] = f2bf(f0.y); a[2] = f2bf(f0.z); a[3] = f2bf(f0.w);
      a[4] = f2bf(f1.x); a[5] = f2bf(f1.y); a[6] = f2bf(f1.z); a[7] = f2bf(f1.w);
    }
    #pragma unroll
    for (int nt = 0; nt < 4; ++nt)
      acc[mt][nt] = __builtin_amdgcn_mfma_f32_16x16x32_bf16(a, bfr[nt], acc[mt][nt], 0, 0, 0);
  }

  float db0v[4], dW1v[4];
  #pragma unroll
  for (int nt = 0; nt < 4; ++nt) {
    int h = nt * 16 + lrow;
    db0v[nt] = db0[xx * NH + h];
    dW1v[nt] = dW1[xx * NH + h];
  }
  const float lv = lvd[d];
  const float inv_std = expf(-0.5f * lv);
  const float cterm = -0.5f * lv - 0.5f * LOG2PI_F;
  const float b1v = db1[xx];

  float racc = 0.0f;
  #pragma unroll
  for (int mt = 0; mt < 4; ++mt) {
    #pragma unroll
    for (int reg = 0; reg < 4; ++reg) {
      float v = 0.0f;
      #pragma unroll
      for (int nt = 0; nt < 4; ++nt) {
        float hv = acc[mt][nt][reg] + db0v[nt];
        hv = fmaxf(hv, 0.01f * hv);
        v += hv * dW1v[nt];
      }
      #pragma unroll
      for (int off = 1; off < 16; off <<= 1) v += __shfl_xor(v, off, 16);
      if (lrow == 0) {
        int b = mb * 256 + w * 64 + mt * 16 + g * 4 + reg;
        float px = v + b1v;
        float e = (y[((size_t)b * ND + d) * NDX + xx] - px) * inv_std;
        racc += -0.5f * e * e + cterm;
      }
    }
  }
  racc += __shfl_xor(racc, 16, 64);
  racc += __shfl_xor(racc, 32, 64);

  __shared__ float rb[4];
  if (l == 0) rb[w] = racc;
  __syncthreads();
  if (threadIdx.x == 0)
    rec_partial[((size_t)d * NDX + xx) * 2 + mb] = rb[0] + rb[1] + rb[2] + rb[3];
}

// =====================================================================
// final reduction -> loss = (sum_kl - sum_recon) / B
// =====================================================================
__global__ __launch_bounds__(256) void k_reduce(
    const float* __restrict__ rp, const float* __restrict__ kp,
    float* __restrict__ out)
{
  __shared__ float sr[4], sk[4];
  float r = 0.f, k = 0.f;
  for (int i = threadIdx.x; i < 2560; i += 256) r += rp[i];
  for (int i = threadIdx.x; i < 640; i += 256) k += kp[i];
  #pragma unroll
  for (int off = 32; off; off >>= 1) {
    r += __shfl_xor(r, off, 64);
    k += __shfl_xor(k, off, 64);
  }
  int wv = threadIdx.x >> 6;
  if ((threadIdx.x & 63) == 0) { sr[wv] = r; sk[wv] = k; }
  __syncthreads();
  if (threadIdx.x == 0) {
    float R = sr[0] + sr[1] + sr[2] + sr[3];
    float K = sk[0] + sk[1] + sk[2] + sk[3];
    out[0] = (K - R) / (float)NB;
  }
}

// =====================================================================
extern "C" void kernel_launch(void* const* d_in, const int* in_sizes, int n_in,
                              void* d_out, int out_size, void* d_ws, size_t ws_size,
                              hipStream_t stream) {
  (void)in_sizes; (void)n_in; (void)out_size; (void)ws_size;
  const float* x        = (const float*)d_in[0];
  const float* y        = (const float*)d_in[1];
  const float* mask_p   = (const float*)d_in[2];
  const float* w_enc    = (const float*)d_in[3];
  const float* w_dec    = (const float*)d_in[4];
  const float* enc_W0   = (const float*)d_in[5];
  const float* enc_b0   = (const float*)d_in[6];
  const float* enc_W1   = (const float*)d_in[7];
  const float* enc_b1   = (const float*)d_in[8];
  const float* dec_W0   = (const float*)d_in[9];
  const float* dec_b0   = (const float*)d_in[10];
  const float* dec_W1   = (const float*)d_in[11];
  const float* dec_b1   = (const float*)d_in[12];
  const float* t_W0     = (const float*)d_in[13];
  const float* t_b0     = (const float*)d_in[14];
  const float* t_W1     = (const float*)d_in[15];
  const float* t_b1     = (const float*)d_in[16];
  const float* lv_enc   = (const float*)d_in[17];
  const float* lv_dec   = (const float*)d_in[18];
  const float* t_logvar = (const float*)d_in[19];

  float* ws     = (float*)d_ws;
  float* z_past = ws;                         // 163840 f32
  float* mu_t   = z_past + 163840;            // 40960
  float* z_t    = mu_t + 40960;               // 40960
  float* rec_p  = z_t + 40960;                // 2560
  float* kl_p   = rec_p + 2560;               // 640
  float* em     = kl_p + 640;                 // 25600
  float* mu_all = em + 25600;                 // 204800
  short* Abf    = (short*)(mu_all + 204800);  // 5*2560*256
  short* PtE    = Abf + 5 * NSAMP * NDX;      // 5*1024*256
  short* QtD    = PtE + 5 * 1024 * NDX;       // 5*256*64*32
  short* TtB    = QtD + 5 * NDX * NH * 32;    // 80*64*320

  k_prepW<<<18740, 256, 0, stream>>>(
      x, y, Abf, w_enc, enc_W0, PtE, w_dec, dec_W0, QtD, mask_p, em, t_W0, TtB);

  k_enc_mfma<<<dim3(NSAMP / 64, 4, ND), 256, 0, stream>>>(
      Abf, PtE, enc_b0, enc_W1, enc_b1, mu_all);
  k_noise<<<NSAMP * NM / 256, 256, 0, stream>>>(mu_all, lv_enc, z_past, mu_t, z_t);
  k_trans_mfma<<<dim3(NB / 64, NM), 256, 0, stream>>>(
      em, z_past, TtB, t_b0, t_W1, t_b1, lv_enc, t_logvar, mu_t, kl_p);
  k_dec_mfma<<<dim3(2, NDX, ND), 256, 0, stream>>>(
      z_t, QtD, y, dec_b0, dec_W1, dec_b1, lv_dec, rec_p);
  k_reduce<<<1, 256, 0, stream>>>(rec_p, kl_p, (float*)d_out);
}

// Round 6
// 116.171 us; speedup vs baseline: 5.5422x; 1.0608x over previous
//
#include <hip/hip_runtime.h>
#include <cstdint>

// ---- problem dims ----
constexpr int NB = 512, NTAU = 4, ND = 5, NDX = 256, NDZ = 16, NH = 64;
constexpr int NM  = ND * NDZ;          // 80
constexpr int NTM = NTAU * NM;         // 320
constexpr int NSAMP = NB * NTAU + NB;  // 2560 (past samples then t samples)
constexpr float LOG2PI_F = 1.8378770664093453f;

typedef __attribute__((ext_vector_type(8))) short bf16x8;
typedef __attribute__((ext_vector_type(4))) float f32x4;

// ---- counter-based RNG (distribution-exact stand-in for jax.random) ----
__device__ __forceinline__ unsigned long long mix64(unsigned long long z) {
  z += 0x9E3779B97F4A7C15ull;
  z = (z ^ (z >> 30)) * 0xBF58476D1CE4E5B9ull;
  z = (z ^ (z >> 27)) * 0x94D049BB133111EBull;
  return z ^ (z >> 31);
}
__device__ __forceinline__ float u01f(unsigned long long h) {
  return ((float)(unsigned)(h >> 40) + 0.5f) * (1.0f / 16777216.0f);
}
__device__ __forceinline__ float rng_normal(unsigned long long salt, unsigned long long idx) {
  float u1 = u01f(mix64(salt + 2ull * idx));
  float u2 = u01f(mix64(salt + 2ull * idx + 1ull));
  float r = sqrtf(-2.0f * logf(u1));
  return r * cosf(6.283185307179586f * u2);
}
constexpr unsigned long long SALT_ADJ = 0x1000000000000ull;
constexpr unsigned long long SALT_EP  = 0x2000000000000ull;
constexpr unsigned long long SALT_ET  = 0x3000000000000ull;

__device__ __forceinline__ short f2bf(float f) {
  unsigned u = __float_as_uint(f);
  unsigned r = (u + 0x7FFFu + ((u >> 16) & 1u)) >> 16;
  return (short)r;
}

// =====================================================================
// k_prepW: all bf16 operand materialization, one launch.
// block ranges: [0,12800) A, [12800,17920) P, [17920,18240) Q,
//               [18240,18340) EM, [18340,18740) T
// =====================================================================
__global__ __launch_bounds__(256) void k_prepW(
    const float* __restrict__ x, const float* __restrict__ y, short* __restrict__ Abf,
    const float* __restrict__ w_enc, const float* __restrict__ eW0, short* __restrict__ PtE,
    const float* __restrict__ w_dec, const float* __restrict__ dW0, short* __restrict__ QtD,
    const float* __restrict__ mask_param, float* __restrict__ em,
    const float* __restrict__ tW0, short* __restrict__ TtB)
{
  __shared__ short lds[64][65];
  const int bid = blockIdx.x;
  if (bid < 12800) {
    int idx = bid * 256 + threadIdx.x;
    int d = idx / (NSAMP * NDX);
    int r = idx % (NSAMP * NDX);
    int s = r >> 8, xx = r & 255;
    float v = (s < NB * NTAU) ? x[((size_t)s * ND + d) * NDX + xx]
                              : y[((size_t)(s - NB * NTAU) * ND + d) * NDX + xx];
    Abf[idx] = f2bf(v);
  } else if (bid < 17920) {
    int idx = (bid - 12800) * 256 + threadIdx.x;
    int d = idx / (1024 * NDX);
    int r = idx % (1024 * NDX);
    int col = r >> 8, xx = r & 255;
    int z = col >> 6, h = col & 63;
    float v = w_enc[((size_t)d * NDZ + z) * NDX + xx] * eW0[((size_t)z * NDX + xx) * NH + h];
    PtE[idx] = f2bf(v);
  } else if (bid < 18240) {
    int t = (bid - 17920) * 256 + threadIdx.x;
    int d = t / (NDX * NH);
    int r = t % (NDX * NH);
    int xx = r >> 6, h = r & 63;
    size_t base = (size_t)t * 32;
    #pragma unroll
    for (int z = 0; z < NDZ; ++z)
      QtD[base + z] = f2bf(w_dec[((size_t)d * NDX + xx) * NDZ + z] *
                           dW0[((size_t)xx * NDZ + z) * NH + h]);
    #pragma unroll
    for (int z = NDZ; z < 32; ++z) QtD[base + z] = 0;
  } else if (bid < 18340) {
    int idx = (bid - 18240) * 256 + threadIdx.x;
    em[idx] = expf(-mask_param[idx]);
  } else {
    int r = bid - 18340;
    int kt = r % 5, m = r / 5;
    int k0 = kt * 64;
    for (int idx = threadIdx.x; idx < 64 * 64; idx += 256) {
      int hh = idx & 63, kk = idx >> 6;
      lds[kk][hh] = f2bf(tW0[((size_t)m * NTM + k0 + kk) * NH + hh]);
    }
    __syncthreads();
    for (int idx = threadIdx.x; idx < 64 * 64; idx += 256) {
      int kk = idx & 63, hh = idx >> 6;
      TtB[((size_t)m * NH + hh) * NTM + k0 + kk] = lds[kk][hh];
    }
  }
}

// =====================================================================
// encoder GEMM: LDS-shared B per z, A resident, 4-z loop
// grid (40 sb, 4 zq, 5 d), block 256 (4 waves x 16 s-rows)
// =====================================================================
__global__ __launch_bounds__(256) void k_enc_mfma(
    const short* __restrict__ Abf, const short* __restrict__ PtE,
    const float* __restrict__ b0, const float* __restrict__ W1,
    const float* __restrict__ b1, float* __restrict__ mu_all)
{
  __shared__ __align__(16) short Bs[64 * 264];

  const int d = blockIdx.z, zq = blockIdx.y;
  const int s0 = blockIdx.x * 64;
  const int tid = threadIdx.x;
  const int w = tid >> 6, l = tid & 63;
  const int lrow = l & 15, g = l >> 4;

  const short* Arow = Abf + ((size_t)(d * NSAMP + s0 + w * 16 + lrow)) * NDX + g * 8;
  bf16x8 a[8];
  #pragma unroll
  for (int ks = 0; ks < 8; ++ks) a[ks] = *(const bf16x8*)(Arow + ks * 32);

  const int stg_row = tid >> 2;
  const int stg_cg  = tid & 3;

  for (int zi = 0; zi < 4; ++zi) {
    const int z = zq * 4 + zi;
    {
      const short* src = PtE + ((size_t)(d * 1024 + z * 64 + stg_row)) * NDX + stg_cg * 64;
      short* dst = Bs + stg_row * 264 + stg_cg * 64;
      #pragma unroll
      for (int j = 0; j < 8; ++j)
        *(bf16x8*)(dst + j * 8) = *(const bf16x8*)(src + j * 8);
    }
    __syncthreads();

    f32x4 acc[4] = {};
    #pragma unroll
    for (int nt = 0; nt < 4; ++nt) {
      const short* Brow = Bs + (nt * 16 + lrow) * 264 + g * 8;
      #pragma unroll
      for (int ks = 0; ks < 8; ++ks) {
        bf16x8 bv = *(const bf16x8*)(Brow + ks * 32);
        acc[nt] = __builtin_amdgcn_mfma_f32_16x16x32_bf16(a[ks], bv, acc[nt], 0, 0, 0);
      }
    }

    float b0v[4], w1v[4];
    #pragma unroll
    for (int nt = 0; nt < 4; ++nt) {
      int h = nt * 16 + lrow;
      b0v[nt] = b0[z * NH + h];
      w1v[nt] = W1[z * NH + h];
    }
    const float b1v = b1[z];
    #pragma unroll
    for (int reg = 0; reg < 4; ++reg) {
      float v = 0.0f;
      #pragma unroll
      for (int nt = 0; nt < 4; ++nt) {
        float hv = acc[nt][reg] + b0v[nt];
        hv = fmaxf(hv, 0.01f * hv);
        v += hv * w1v[nt];
      }
      #pragma unroll
      for (int off = 1; off < 16; off <<= 1) v += __shfl_xor(v, off, 16);
      if (lrow == 0) {
        int s = s0 + w * 16 + g * 4 + reg;
        mu_all[(size_t)s * NM + d * NDZ + z] = v + b1v;
      }
    }
    __syncthreads();
  }
}

// =====================================================================
// reparameterization: one thread per (s, m) element
// =====================================================================
__global__ __launch_bounds__(256) void k_noise(
    const float* __restrict__ mu_all, const float* __restrict__ lve,
    float* __restrict__ z_past, float* __restrict__ mu_t, float* __restrict__ z_t)
{
  int i = blockIdx.x * 256 + threadIdx.x;   // < 2560*80
  int s = i / NM, m = i - s * NM;
  int d = m >> 4;
  float mu = mu_all[i];
  float qs = expf(0.5f * lve[d]);
  if (s < NB * NTAU) {
    float eps = rng_normal(SALT_EP, (unsigned long long)s * NM + m);
    z_past[i] = mu + qs * eps;
  } else {
    int b = s - NB * NTAU;
    float eps = rng_normal(SALT_ET, (unsigned long long)b * NM + m);
    size_t o = (size_t)b * NM + m;
    mu_t[o] = mu;
    z_t[o]  = mu + qs * eps;
  }
}

// =====================================================================
// gating: gated[m][b][tm] = bf16( adj * z_past[b][tm] )
// 4 gates per thread; 2 uniforms per mix64; fast rcp for the sigmoid algebra
// grid (80*512*80/256 = 12800), block 256
// =====================================================================
__global__ __launch_bounds__(256) void k_gated(
    const float* __restrict__ em, const float* __restrict__ z_past,
    short* __restrict__ gated)
{
  int i = blockIdx.x * 256 + threadIdx.x;   // < 80*512*80
  int j = i % 80;                           // tm0 = 4*j
  int r = i / 80;
  int b = r % NB;
  int m = r / NB;
  int tm0 = j * 4;
  int t = tm0 / NM;                         // tm0..tm0+3 stay within one t (80%4==0)
  int s0 = tm0 - t * NM;

  unsigned long long aibase =
      ((unsigned long long)((b * NTAU + t) * NM + m)) * NM + s0;
  unsigned long long h0 = mix64(SALT_ADJ + aibase);
  unsigned long long h1 = mix64(SALT_ADJ + aibase + 2);
  float u[4];
  u[0] = ((float)(unsigned)(h0 >> 40) + 0.5f) * (1.0f / 16777216.0f);
  u[1] = ((float)((unsigned)(h0 >> 16) & 0xFFFFFFu) + 0.5f) * (1.0f / 16777216.0f);
  u[2] = ((float)(unsigned)(h1 >> 40) + 0.5f) * (1.0f / 16777216.0f);
  u[3] = ((float)((unsigned)(h1 >> 16) & 0xFFFFFFu) + 0.5f) * (1.0f / 16777216.0f);

  float4 ev = *(const float4*)&em[(t * NM + m) * NM + s0];
  float4 zv = *(const float4*)&z_past[(size_t)b * NTM + tm0];
  const float* evp = &ev.x;
  const float* zvp = &zv.x;

  short out[4];
  #pragma unroll
  for (int k = 0; k < 4; ++k) {
    float uu = fminf(fmaxf(u[k], 1e-6f), 1.0f - 1e-6f);
    float den = fmaf(evp[k], 1.0f - uu, uu);
    float adj = uu * __builtin_amdgcn_rcpf(den);
    out[k] = f2bf(adj * zvp[k]);
  }
  *(short4*)&gated[((size_t)m * NB + b) * NTM + tm0] =
      make_short4(out[0], out[1], out[2], out[3]);
}

// =====================================================================
// transition GEMM + KL: pz[b, m*64+h] via MFMA over K=320, fused KL
// grid (NB/64, NM), block 256 (4 waves x 16 rows x 64 cols)
// =====================================================================
__global__ __launch_bounds__(256) void k_trans_mfma(
    const short* __restrict__ gated, const short* __restrict__ TtB,
    const float* __restrict__ tb0, const float* __restrict__ tW1,
    const float* __restrict__ tb1, const float* __restrict__ lve,
    const float* __restrict__ t_logvar, const float* __restrict__ mu_t,
    float* __restrict__ kl_partial)
{
  const int m = blockIdx.y;
  const int b0 = blockIdx.x * 64;
  const int w = threadIdx.x >> 6, l = threadIdx.x & 63;
  const int lrow = l & 15, g = l >> 4;

  const short* Arow = gated + ((size_t)(m * NB + b0 + w * 16 + lrow)) * NTM + g * 8;
  bf16x8 a[10];
  #pragma unroll
  for (int ks = 0; ks < 10; ++ks) a[ks] = *(const bf16x8*)(Arow + ks * 32);

  f32x4 acc[4] = {};
  #pragma unroll
  for (int nt = 0; nt < 4; ++nt) {
    const short* Brow = TtB + ((size_t)(m * NH + nt * 16 + lrow)) * NTM + g * 8;
    #pragma unroll
    for (int ks = 0; ks < 10; ++ks) {
      bf16x8 bv = *(const bf16x8*)(Brow + ks * 32);
      acc[nt] = __builtin_amdgcn_mfma_f32_16x16x32_bf16(a[ks], bv, acc[nt], 0, 0, 0);
    }
  }

  float b0v[4], w1v[4];
  #pragma unroll
  for (int nt = 0; nt < 4; ++nt) {
    int h = nt * 16 + lrow;
    b0v[nt] = tb0[m * NH + h];
    w1v[nt] = tW1[m * NH + h];
  }

  const int d = m >> 4;
  const float lv_t = t_logvar[m];
  const float lv_e = lve[d];
  const float inv2var = 0.5f * expf(-lv_t);
  const float qvar = expf(lv_e);
  const float cterm = 0.5f * lv_t - 0.5f * lv_e - 0.5f;
  const float bv1 = tb1[m];

  float klw = 0.0f;
  #pragma unroll
  for (int reg = 0; reg < 4; ++reg) {
    float v = 0.0f;
    #pragma unroll
    for (int nt = 0; nt < 4; ++nt) {
      float hv = acc[nt][reg] + b0v[nt];
      hv = fmaxf(hv, 0.01f * hv);
      v += hv * w1v[nt];
    }
    #pragma unroll
    for (int off = 1; off < 16; off <<= 1) v += __shfl_xor(v, off, 16);
    if (lrow == 0) {
      int b = b0 + w * 16 + g * 4 + reg;
      float pz = v + bv1;
      float diff = mu_t[(size_t)b * NM + m] - pz;
      klw += cterm + (qvar + diff * diff) * inv2var;
    }
  }
  klw += __shfl_xor(klw, 16, 64);
  klw += __shfl_xor(klw, 32, 64);

  __shared__ float klb[4];
  if (l == 0) klb[w] = klw;
  __syncthreads();
  if (threadIdx.x == 0)
    kl_partial[blockIdx.x * NM + m] = klb[0] + klb[1] + klb[2] + klb[3];
}

// =====================================================================
// decoder: K=32 padded MFMA, fused recon partial sums
// grid (2, 256 xx, 5 d), block 256
// =====================================================================
__global__ __launch_bounds__(256) void k_dec_mfma(
    const float* __restrict__ zt, const short* __restrict__ QtD,
    const float* __restrict__ y, const float* __restrict__ db0,
    const float* __restrict__ dW1, const float* __restrict__ db1,
    const float* __restrict__ lvd, float* __restrict__ rec_partial)
{
  const int d = blockIdx.z, xx = blockIdx.y, mb = blockIdx.x;
  const int w = threadIdx.x >> 6, l = threadIdx.x & 63;
  const int lrow = l & 15, g = l >> 4;

  bf16x8 bfr[4];
  const short* Bbase = QtD + ((size_t)((d * NDX + xx) * NH)) * 32;
  #pragma unroll
  for (int nt = 0; nt < 4; ++nt)
    bfr[nt] = *(const bf16x8*)(Bbase + (nt * 16 + lrow) * 32 + g * 8);

  f32x4 acc[4][4] = {};
  #pragma unroll
  for (int mt = 0; mt < 4; ++mt) {
    int b = mb * 256 + w * 64 + mt * 16 + lrow;
    bf16x8 a = {0, 0, 0, 0, 0, 0, 0, 0};
    if (g < 2) {
      const float* zp = zt + (size_t)b * NM + d * NDZ + g * 8;
      float4 f0 = *(const float4*)zp;
      float4 f1 = *(const float4*)(zp + 4);
      a[0] = f2bf(f0.x); a[1] = f2bf(f0.y); a[2] = f2bf(f0.z); a[3] = f2bf(f0.w);
      a[4] = f2bf(f1.x); a[5] = f2bf(f1.y); a[6] = f2bf(f1.z); a[7] = f2bf(f1.w);
    }
    #pragma unroll
    for (int nt = 0; nt < 4; ++nt)
      acc[mt][nt] = __builtin_amdgcn_mfma_f32_16x16x32_bf16(a, bfr[nt], acc[mt][nt], 0, 0, 0);
  }

  float db0v[4], dW1v[4];
  #pragma unroll
  for (int nt = 0; nt < 4; ++nt) {
    int h = nt * 16 + lrow;
    db0v[nt] = db0[xx * NH + h];
    dW1v[nt] = dW1[xx * NH + h];
  }
  const float lv = lvd[d];
  const float inv_std = expf(-0.5f * lv);
  const float cterm = -0.5f * lv - 0.5f * LOG2PI_F;
  const float b1v = db1[xx];

  float racc = 0.0f;
  #pragma unroll
  for (int mt = 0; mt < 4; ++mt) {
    #pragma unroll
    for (int reg = 0; reg < 4; ++reg) {
      float v = 0.0f;
      #pragma unroll
      for (int nt = 0; nt < 4; ++nt) {
        float hv = acc[mt][nt][reg] + db0v[nt];
        hv = fmaxf(hv, 0.01f * hv);
        v += hv * dW1v[nt];
      }
      #pragma unroll
      for (int off = 1; off < 16; off <<= 1) v += __shfl_xor(v, off, 16);
      if (lrow == 0) {
        int b = mb * 256 + w * 64 + mt * 16 + g * 4 + reg;
        float px = v + b1v;
        float e = (y[((size_t)b * ND + d) * NDX + xx] - px) * inv_std;
        racc += -0.5f * e * e + cterm;
      }
    }
  }
  racc += __shfl_xor(racc, 16, 64);
  racc += __shfl_xor(racc, 32, 64);

  __shared__ float rb[4];
  if (l == 0) rb[w] = racc;
  __syncthreads();
  if (threadIdx.x == 0)
    rec_partial[((size_t)d * NDX + xx) * 2 + mb] = rb[0] + rb[1] + rb[2] + rb[3];
}

// =====================================================================
// final reduction -> loss = (sum_kl - sum_recon) / B
// =====================================================================
__global__ __launch_bounds__(256) void k_reduce(
    const float* __restrict__ rp, const float* __restrict__ kp,
    float* __restrict__ out)
{
  __shared__ float sr[4], sk[4];
  float r = 0.f, k = 0.f;
  for (int i = threadIdx.x; i < 2560; i += 256) r += rp[i];
  for (int i = threadIdx.x; i < 640; i += 256) k += kp[i];
  #pragma unroll
  for (int off = 32; off; off >>= 1) {
    r += __shfl_xor(r, off, 64);
    k += __shfl_xor(k, off, 64);
  }
  int wv = threadIdx.x >> 6;
  if ((threadIdx.x & 63) == 0) { sr[wv] = r; sk[wv] = k; }
  __syncthreads();
  if (threadIdx.x == 0) {
    float R = sr[0] + sr[1] + sr[2] + sr[3];
    float K = sk[0] + sk[1] + sk[2] + sk[3];
    out[0] = (K - R) / (float)NB;
  }
}

// =====================================================================
extern "C" void kernel_launch(void* const* d_in, const int* in_sizes, int n_in,
                              void* d_out, int out_size, void* d_ws, size_t ws_size,
                              hipStream_t stream) {
  (void)in_sizes; (void)n_in; (void)out_size; (void)ws_size;
  const float* x        = (const float*)d_in[0];
  const float* y        = (const float*)d_in[1];
  const float* mask_p   = (const float*)d_in[2];
  const float* w_enc    = (const float*)d_in[3];
  const float* w_dec    = (const float*)d_in[4];
  const float* enc_W0   = (const float*)d_in[5];
  const float* enc_b0   = (const float*)d_in[6];
  const float* enc_W1   = (const float*)d_in[7];
  const float* enc_b1   = (const float*)d_in[8];
  const float* dec_W0   = (const float*)d_in[9];
  const float* dec_b0   = (const float*)d_in[10];
  const float* dec_W1   = (const float*)d_in[11];
  const float* dec_b1   = (const float*)d_in[12];
  const float* t_W0     = (const float*)d_in[13];
  const float* t_b0     = (const float*)d_in[14];
  const float* t_W1     = (const float*)d_in[15];
  const float* t_b1     = (const float*)d_in[16];
  const float* lv_enc   = (const float*)d_in[17];
  const float* lv_dec   = (const float*)d_in[18];
  const float* t_logvar = (const float*)d_in[19];

  float* ws     = (float*)d_ws;
  float* z_past = ws;                         // 163840 f32
  float* mu_t   = z_past + 163840;            // 40960
  float* z_t    = mu_t + 40960;               // 40960
  float* rec_p  = z_t + 40960;                // 2560
  float* kl_p   = rec_p + 2560;               // 640
  float* em     = kl_p + 640;                 // 25600
  float* mu_all = em + 25600;                 // 204800
  short* Abf    = (short*)(mu_all + 204800);  // 5*2560*256
  short* PtE    = Abf + 5 * NSAMP * NDX;      // 5*1024*256
  short* QtD    = PtE + 5 * 1024 * NDX;       // 5*256*64*32
  short* TtB    = QtD + 5 * NDX * NH * 32;    // 80*64*320
  short* gated  = TtB + NM * NH * NTM;        // 80*512*320 (26.2 MB)

  k_prepW<<<18740, 256, 0, stream>>>(
      x, y, Abf, w_enc, enc_W0, PtE, w_dec, dec_W0, QtD, mask_p, em, t_W0, TtB);

  k_enc_mfma<<<dim3(NSAMP / 64, 4, ND), 256, 0, stream>>>(
      Abf, PtE, enc_b0, enc_W1, enc_b1, mu_all);
  k_noise<<<NSAMP * NM / 256, 256, 0, stream>>>(mu_all, lv_enc, z_past, mu_t, z_t);
  k_gated<<<NM * NB * 80 / 256, 256, 0, stream>>>(em, z_past, gated);
  k_trans_mfma<<<dim3(NB / 64, NM), 256, 0, stream>>>(
      gated, TtB, t_b0, t_W1, t_b1, lv_enc, t_logvar, mu_t, kl_p);
  k_dec_mfma<<<dim3(2, NDX, ND), 256, 0, stream>>>(
      z_t, QtD, y, dec_b0, dec_W1, dec_b1, lv_dec, rec_p);
  k_reduce<<<1, 256, 0, stream>>>(rec_p, kl_p, (float*)d_out);
}

// Round 7
// 89.868 us; speedup vs baseline: 7.1643x; 1.2927x over previous
//
#include <hip/hip_runtime.h>
#include <cstdint>

// ---- problem dims ----
constexpr int NB = 512, NTAU = 4, ND = 5, NDX = 256, NDZ = 16, NH = 64;
constexpr int NM  = ND * NDZ;          // 80
constexpr int NTM = NTAU * NM;         // 320
constexpr int NSAMP = NB * NTAU + NB;  // 2560 (past samples then t samples)
constexpr float LOG2PI_F = 1.8378770664093453f;

typedef __attribute__((ext_vector_type(8))) short bf16x8;
typedef __attribute__((ext_vector_type(4))) float f32x4;

// ---- counter-based RNG (distribution-exact stand-in for jax.random) ----
__device__ __forceinline__ unsigned long long mix64(unsigned long long z) {
  z += 0x9E3779B97F4A7C15ull;
  z = (z ^ (z >> 30)) * 0xBF58476D1CE4E5B9ull;
  z = (z ^ (z >> 27)) * 0x94D049BB133111EBull;
  return z ^ (z >> 31);
}
__device__ __forceinline__ float u01f(unsigned long long h) {
  return ((float)(unsigned)(h >> 40) + 0.5f) * (1.0f / 16777216.0f);
}
__device__ __forceinline__ float rng_normal(unsigned long long salt, unsigned long long idx) {
  float u1 = u01f(mix64(salt + 2ull * idx));
  float u2 = u01f(mix64(salt + 2ull * idx + 1ull));
  float r = sqrtf(-2.0f * logf(u1));
  return r * cosf(6.283185307179586f * u2);
}
constexpr unsigned long long SALT_ADJ = 0x1000000000000ull;
constexpr unsigned long long SALT_EP  = 0x2000000000000ull;
constexpr unsigned long long SALT_ET  = 0x3000000000000ull;

__device__ __forceinline__ short f2bf(float f) {
  unsigned u = __float_as_uint(f);
  unsigned r = (u + 0x7FFFu + ((u >> 16) & 1u)) >> 16;
  return (short)r;
}

// =====================================================================
// k_prepW: operand materialization, one launch. block ranges:
// [0,1600) A vec8, [1600,6720) P, [6720,7040) Q, [7040,7140) EM,
// [7140,7540) T, [7540,8180) yT
// =====================================================================
__global__ __launch_bounds__(256) void k_prepW(
    const float* __restrict__ x, const float* __restrict__ y, short* __restrict__ Abf,
    const float* __restrict__ w_enc, const float* __restrict__ eW0, short* __restrict__ PtE,
    const float* __restrict__ w_dec, const float* __restrict__ dW0, short* __restrict__ QtD,
    const float* __restrict__ mask_param, float* __restrict__ em,
    const float* __restrict__ tW0, short* __restrict__ TtB,
    float* __restrict__ yT)
{
  __shared__ short lds[64][65];
  const int bid = blockIdx.x;
  if (bid < 1600) {
    // Abf[d][s][x0..x0+7] vectorized
    int e0 = (bid * 256 + threadIdx.x) * 8;
    int d = e0 / (NSAMP * NDX);
    int r = e0 % (NSAMP * NDX);
    int s = r >> 8, x0 = r & 255;
    const float* src = (s < NB * NTAU)
        ? &x[((size_t)s * ND + d) * NDX + x0]
        : &y[((size_t)(s - NB * NTAU) * ND + d) * NDX + x0];
    float4 f0 = *(const float4*)src;
    float4 f1 = *(const float4*)(src + 4);
    bf16x8 o;
    o[0] = f2bf(f0.x); o[1] = f2bf(f0.y); o[2] = f2bf(f0.z); o[3] = f2bf(f0.w);
    o[4] = f2bf(f1.x); o[5] = f2bf(f1.y); o[6] = f2bf(f1.z); o[7] = f2bf(f1.w);
    *(bf16x8*)&Abf[e0] = o;
  } else if (bid < 6720) {
    // PtE[d][col=z*64+h][xx] = w_enc[d,z,xx] * eW0[z,xx,h]
    int idx = (bid - 1600) * 256 + threadIdx.x;
    int d = idx / (1024 * NDX);
    int r = idx % (1024 * NDX);
    int col = r >> 8, xx = r & 255;
    int z = col >> 6, h = col & 63;
    float v = w_enc[((size_t)d * NDZ + z) * NDX + xx] * eW0[((size_t)z * NDX + xx) * NH + h];
    PtE[idx] = f2bf(v);
  } else if (bid < 7040) {
    int t = (bid - 6720) * 256 + threadIdx.x;
    int d = t / (NDX * NH);
    int r = t % (NDX * NH);
    int xx = r >> 6, h = r & 63;
    size_t base = (size_t)t * 32;
    #pragma unroll
    for (int z = 0; z < NDZ; ++z)
      QtD[base + z] = f2bf(w_dec[((size_t)d * NDX + xx) * NDZ + z] *
                           dW0[((size_t)xx * NDZ + z) * NH + h]);
    #pragma unroll
    for (int z = NDZ; z < 32; ++z) QtD[base + z] = 0;
  } else if (bid < 7140) {
    int idx = (bid - 7040) * 256 + threadIdx.x;
    em[idx] = expf(-mask_param[idx]);
  } else if (bid < 7540) {
    int r = bid - 7140;
    int kt = r % 5, m = r / 5;
    int k0 = kt * 64;
    for (int idx = threadIdx.x; idx < 64 * 64; idx += 256) {
      int hh = idx & 63, kk = idx >> 6;
      lds[kk][hh] = f2bf(tW0[((size_t)m * NTM + k0 + kk) * NH + hh]);
    }
    __syncthreads();
    for (int idx = threadIdx.x; idx < 64 * 64; idx += 256) {
      int kk = idx & 63, hh = idx >> 6;
      TtB[((size_t)m * NH + hh) * NTM + k0 + kk] = lds[kk][hh];
    }
  } else {
    // yT[d][xx][b] = y[b][d][xx], 4 b's per thread
    int e0 = ((bid - 7540) * 256 + threadIdx.x) * 4;
    int d = e0 / (NDX * NB);
    int rem = e0 % (NDX * NB);
    int xx = rem >> 9, b0 = rem & 511;
    float4 o;
    o.x = y[((size_t)(b0 + 0) * ND + d) * NDX + xx];
    o.y = y[((size_t)(b0 + 1) * ND + d) * NDX + xx];
    o.z = y[((size_t)(b0 + 2) * ND + d) * NDX + xx];
    o.w = y[((size_t)(b0 + 3) * ND + d) * NDX + xx];
    *(float4*)&yT[e0] = o;
  }
}

// =====================================================================
// encoder GEMM v5: 512 thr (8 waves x 16 rows = 128 samples), 4-z loop,
// LDS-shared B per z. grid (20 sb, 4 zq, 5 d)
// =====================================================================
__global__ __launch_bounds__(512) void k_enc_mfma(
    const short* __restrict__ Abf, const short* __restrict__ PtE,
    const float* __restrict__ b0, const float* __restrict__ W1,
    const float* __restrict__ b1, float* __restrict__ mu_all)
{
  __shared__ __align__(16) short Bs[64 * 264];

  const int d = blockIdx.z, zq = blockIdx.y;
  const int s0 = blockIdx.x * 128;
  const int tid = threadIdx.x;
  const int w = tid >> 6, l = tid & 63;
  const int lrow = l & 15, g = l >> 4;

  const short* Arow = Abf + ((size_t)(d * NSAMP + s0 + w * 16 + lrow)) * NDX + g * 8;
  bf16x8 a[8];
  #pragma unroll
  for (int ks = 0; ks < 8; ++ks) a[ks] = *(const bf16x8*)(Arow + ks * 32);

  const int stg_row = tid >> 3;        // 0..63
  const int stg_c   = (tid & 7) * 32;  // 32-short chunk

  for (int zi = 0; zi < 4; ++zi) {
    const int z = zq * 4 + zi;
    {
      const short* src = PtE + ((size_t)(d * 1024 + z * 64 + stg_row)) * NDX + stg_c;
      short* dst = Bs + stg_row * 264 + stg_c;
      #pragma unroll
      for (int j = 0; j < 4; ++j)
        *(bf16x8*)(dst + j * 8) = *(const bf16x8*)(src + j * 8);
    }
    __syncthreads();

    f32x4 acc[4] = {};
    #pragma unroll
    for (int nt = 0; nt < 4; ++nt) {
      const short* Brow = Bs + (nt * 16 + lrow) * 264 + g * 8;
      #pragma unroll
      for (int ks = 0; ks < 8; ++ks) {
        bf16x8 bv = *(const bf16x8*)(Brow + ks * 32);
        acc[nt] = __builtin_amdgcn_mfma_f32_16x16x32_bf16(a[ks], bv, acc[nt], 0, 0, 0);
      }
    }

    float b0v[4], w1v[4];
    #pragma unroll
    for (int nt = 0; nt < 4; ++nt) {
      int h = nt * 16 + lrow;
      b0v[nt] = b0[z * NH + h];
      w1v[nt] = W1[z * NH + h];
    }
    const float b1v = b1[z];
    #pragma unroll
    for (int reg = 0; reg < 4; ++reg) {
      float v = 0.0f;
      #pragma unroll
      for (int nt = 0; nt < 4; ++nt) {
        float hv = acc[nt][reg] + b0v[nt];
        hv = fmaxf(hv, 0.01f * hv);
        v += hv * w1v[nt];
      }
      #pragma unroll
      for (int off = 1; off < 16; off <<= 1) v += __shfl_xor(v, off, 16);
      if (lrow == 0) {
        int s = s0 + w * 16 + g * 4 + reg;
        mu_all[(size_t)s * NM + d * NDZ + z] = v + b1v;
      }
    }
    __syncthreads();
  }
}

// =====================================================================
// reparameterization: one thread per (s, m) element
// =====================================================================
__global__ __launch_bounds__(256) void k_noise(
    const float* __restrict__ mu_all, const float* __restrict__ lve,
    float* __restrict__ z_past, float* __restrict__ mu_t, float* __restrict__ z_t)
{
  int i = blockIdx.x * 256 + threadIdx.x;   // < 2560*80
  int s = i / NM, m = i - s * NM;
  int d = m >> 4;
  float mu = mu_all[i];
  float qs = expf(0.5f * lve[d]);
  if (s < NB * NTAU) {
    float eps = rng_normal(SALT_EP, (unsigned long long)s * NM + m);
    z_past[i] = mu + qs * eps;
  } else {
    int b = s - NB * NTAU;
    float eps = rng_normal(SALT_ET, (unsigned long long)b * NM + m);
    size_t o = (size_t)b * NM + m;
    mu_t[o] = mu;
    z_t[o]  = mu + qs * eps;
  }
}

// =====================================================================
// gating: gated[m][b][tm] = bf16( adj * z_past[b][tm] ), 4 gates/thread
// grid 12800, block 256
// =====================================================================
__global__ __launch_bounds__(256) void k_gated(
    const float* __restrict__ em, const float* __restrict__ z_past,
    short* __restrict__ gated)
{
  int i = blockIdx.x * 256 + threadIdx.x;   // < 80*512*80
  int j = i % 80;
  int r = i / 80;
  int b = r % NB;
  int m = r / NB;
  int tm0 = j * 4;
  int t = tm0 / NM;
  int s0 = tm0 - t * NM;

  unsigned long long aibase =
      ((unsigned long long)((b * NTAU + t) * NM + m)) * NM + s0;
  unsigned long long h0 = mix64(SALT_ADJ + aibase);
  unsigned long long h1 = mix64(SALT_ADJ + aibase + 2);
  float u[4];
  u[0] = ((float)(unsigned)(h0 >> 40) + 0.5f) * (1.0f / 16777216.0f);
  u[1] = ((float)((unsigned)(h0 >> 16) & 0xFFFFFFu) + 0.5f) * (1.0f / 16777216.0f);
  u[2] = ((float)(unsigned)(h1 >> 40) + 0.5f) * (1.0f / 16777216.0f);
  u[3] = ((float)((unsigned)(h1 >> 16) & 0xFFFFFFu) + 0.5f) * (1.0f / 16777216.0f);

  float4 ev = *(const float4*)&em[(t * NM + m) * NM + s0];
  float4 zv = *(const float4*)&z_past[(size_t)b * NTM + tm0];
  const float* evp = &ev.x;
  const float* zvp = &zv.x;

  short out[4];
  #pragma unroll
  for (int k = 0; k < 4; ++k) {
    float uu = fminf(fmaxf(u[k], 1e-6f), 1.0f - 1e-6f);
    float den = fmaf(evp[k], 1.0f - uu, uu);
    float adj = uu * __builtin_amdgcn_rcpf(den);
    out[k] = f2bf(adj * zvp[k]);
  }
  *(short4*)&gated[((size_t)m * NB + b) * NTM + tm0] =
      make_short4(out[0], out[1], out[2], out[3]);
}

// =====================================================================
// transition GEMM + KL v3: 512 thr (8 waves x 16 rows = 128 b),
// TtB panel staged in LDS. grid (4 bq, 80 m)
// =====================================================================
__global__ __launch_bounds__(512) void k_trans_mfma(
    const short* __restrict__ gated, const short* __restrict__ TtB,
    const float* __restrict__ tb0, const float* __restrict__ tW1,
    const float* __restrict__ tb1, const float* __restrict__ lve,
    const float* __restrict__ t_logvar, const float* __restrict__ mu_t,
    float* __restrict__ kl_partial)
{
  __shared__ __align__(16) short Bls[64 * 328];
  __shared__ float klb[8];

  const int m = blockIdx.y;
  const int b0 = blockIdx.x * 128;
  const int tid = threadIdx.x;
  const int w = tid >> 6, l = tid & 63;
  const int lrow = l & 15, g = l >> 4;

  // stage B panel: TtB[m][h=0..63][k=0..319] -> Bls[h*328 + k]
  {
    const int r = tid >> 3;             // 0..63
    const int c0 = (tid & 7) * 40;      // 40-short chunk
    const short* src = TtB + ((size_t)(m * NH + r)) * NTM + c0;
    short* dst = Bls + r * 328 + c0;
    #pragma unroll
    for (int j = 0; j < 5; ++j)
      *(bf16x8*)(dst + j * 8) = *(const bf16x8*)(src + j * 8);
  }

  const short* Arow = gated + ((size_t)(m * NB + b0 + w * 16 + lrow)) * NTM + g * 8;
  bf16x8 a[10];
  #pragma unroll
  for (int ks = 0; ks < 10; ++ks) a[ks] = *(const bf16x8*)(Arow + ks * 32);

  __syncthreads();

  f32x4 acc[4] = {};
  #pragma unroll
  for (int nt = 0; nt < 4; ++nt) {
    const short* Brow = Bls + (nt * 16 + lrow) * 328 + g * 8;
    #pragma unroll
    for (int ks = 0; ks < 10; ++ks) {
      bf16x8 bv = *(const bf16x8*)(Brow + ks * 32);
      acc[nt] = __builtin_amdgcn_mfma_f32_16x16x32_bf16(a[ks], bv, acc[nt], 0, 0, 0);
    }
  }

  float b0v[4], w1v[4];
  #pragma unroll
  for (int nt = 0; nt < 4; ++nt) {
    int h = nt * 16 + lrow;
    b0v[nt] = tb0[m * NH + h];
    w1v[nt] = tW1[m * NH + h];
  }

  const int d = m >> 4;
  const float lv_t = t_logvar[m];
  const float lv_e = lve[d];
  const float inv2var = 0.5f * expf(-lv_t);
  const float qvar = expf(lv_e);
  const float cterm = 0.5f * lv_t - 0.5f * lv_e - 0.5f;
  const float bv1 = tb1[m];

  float klw = 0.0f;
  #pragma unroll
  for (int reg = 0; reg < 4; ++reg) {
    float v = 0.0f;
    #pragma unroll
    for (int nt = 0; nt < 4; ++nt) {
      float hv = acc[nt][reg] + b0v[nt];
      hv = fmaxf(hv, 0.01f * hv);
      v += hv * w1v[nt];
    }
    #pragma unroll
    for (int off = 1; off < 16; off <<= 1) v += __shfl_xor(v, off, 16);
    if (lrow == 0) {
      int b = b0 + w * 16 + g * 4 + reg;
      float pz = v + bv1;
      float diff = mu_t[(size_t)b * NM + m] - pz;
      klw += cterm + (qvar + diff * diff) * inv2var;
    }
  }
  klw += __shfl_xor(klw, 16, 64);
  klw += __shfl_xor(klw, 32, 64);

  if (l == 0) klb[w] = klw;
  __syncthreads();
  if (tid == 0) {
    float s = 0.f;
    #pragma unroll
    for (int i = 0; i < 8; ++i) s += klb[i];
    kl_partial[blockIdx.x * NM + m] = s;
  }
}

// =====================================================================
// decoder: K=32 padded MFMA, fused recon partial sums (yT float4 reads)
// grid (2, 256 xx, 5 d), block 256
// =====================================================================
__global__ __launch_bounds__(256) void k_dec_mfma(
    const float* __restrict__ zt, const short* __restrict__ QtD,
    const float* __restrict__ yT, const float* __restrict__ db0,
    const float* __restrict__ dW1, const float* __restrict__ db1,
    const float* __restrict__ lvd, float* __restrict__ rec_partial)
{
  const int d = blockIdx.z, xx = blockIdx.y, mb = blockIdx.x;
  const int w = threadIdx.x >> 6, l = threadIdx.x & 63;
  const int lrow = l & 15, g = l >> 4;

  bf16x8 bfr[4];
  const short* Bbase = QtD + ((size_t)((d * NDX + xx) * NH)) * 32;
  #pragma unroll
  for (int nt = 0; nt < 4; ++nt)
    bfr[nt] = *(const bf16x8*)(Bbase + (nt * 16 + lrow) * 32 + g * 8);

  f32x4 acc[4][4] = {};
  #pragma unroll
  for (int mt = 0; mt < 4; ++mt) {
    int b = mb * 256 + w * 64 + mt * 16 + lrow;
    bf16x8 a = {0, 0, 0, 0, 0, 0, 0, 0};
    if (g < 2) {
      const float* zp = zt + (size_t)b * NM + d * NDZ + g * 8;
      float4 f0 = *(const float4*)zp;
      float4 f1 = *(const float4*)(zp + 4);
      a[0] = f2bf(f0.x); a[1] = f2bf(f0.y); a[2] = f2bf(f0.z); a[3] = f2bf(f0.w);
      a[4] = f2bf(f1.x); a[5] = f2bf(f1.y); a[6] = f2bf(f1.z); a[7] = f2bf(f1.w);
    }
    #pragma unroll
    for (int nt = 0; nt < 4; ++nt)
      acc[mt][nt] = __builtin_amdgcn_mfma_f32_16x16x32_bf16(a, bfr[nt], acc[mt][nt], 0, 0, 0);
  }

  float db0v[4], dW1v[4];
  #pragma unroll
  for (int nt = 0; nt < 4; ++nt) {
    int h = nt * 16 + lrow;
    db0v[nt] = db0[xx * NH + h];
    dW1v[nt] = dW1[xx * NH + h];
  }
  const float lv = lvd[d];
  const float inv_std = expf(-0.5f * lv);
  const float cterm = -0.5f * lv - 0.5f * LOG2PI_F;
  const float b1v = db1[xx];

  float racc = 0.0f;
  #pragma unroll
  for (int mt = 0; mt < 4; ++mt) {
    float rs[4];
    #pragma unroll
    for (int reg = 0; reg < 4; ++reg) {
      float v = 0.0f;
      #pragma unroll
      for (int nt = 0; nt < 4; ++nt) {
        float hv = acc[mt][nt][reg] + db0v[nt];
        hv = fmaxf(hv, 0.01f * hv);
        v += hv * dW1v[nt];
      }
      #pragma unroll
      for (int off = 1; off < 16; off <<= 1) v += __shfl_xor(v, off, 16);
      rs[reg] = v;
    }
    if (lrow == 0) {
      int b = mb * 256 + w * 64 + mt * 16 + g * 4;
      float4 yv = *(const float4*)&yT[((size_t)d * NDX + xx) * NB + b];
      const float* yvp = &yv.x;
      #pragma unroll
      for (int reg = 0; reg < 4; ++reg) {
        float px = rs[reg] + b1v;
        float e = (yvp[reg] - px) * inv_std;
        racc += -0.5f * e * e + cterm;
      }
    }
  }
  racc += __shfl_xor(racc, 16, 64);
  racc += __shfl_xor(racc, 32, 64);

  __shared__ float rb[4];
  if (l == 0) rb[w] = racc;
  __syncthreads();
  if (threadIdx.x == 0)
    rec_partial[((size_t)d * NDX + xx) * 2 + mb] = rb[0] + rb[1] + rb[2] + rb[3];
}

// =====================================================================
// final reduction -> loss = (sum_kl - sum_recon) / B
// =====================================================================
__global__ __launch_bounds__(256) void k_reduce(
    const float* __restrict__ rp, const float* __restrict__ kp,
    float* __restrict__ out)
{
  __shared__ float sr[4], sk[4];
  float r = 0.f, k = 0.f;
  for (int i = threadIdx.x; i < 2560; i += 256) r += rp[i];
  for (int i = threadIdx.x; i < 320; i += 256) k += kp[i];
  #pragma unroll
  for (int off = 32; off; off >>= 1) {
    r += __shfl_xor(r, off, 64);
    k += __shfl_xor(k, off, 64);
  }
  int wv = threadIdx.x >> 6;
  if ((threadIdx.x & 63) == 0) { sr[wv] = r; sk[wv] = k; }
  __syncthreads();
  if (threadIdx.x == 0) {
    float R = sr[0] + sr[1] + sr[2] + sr[3];
    float K = sk[0] + sk[1] + sk[2] + sk[3];
    out[0] = (K - R) / (float)NB;
  }
}

// =====================================================================
extern "C" void kernel_launch(void* const* d_in, const int* in_sizes, int n_in,
                              void* d_out, int out_size, void* d_ws, size_t ws_size,
                              hipStream_t stream) {
  (void)in_sizes; (void)n_in; (void)out_size; (void)ws_size;
  const float* x        = (const float*)d_in[0];
  const float* y        = (const float*)d_in[1];
  const float* mask_p   = (const float*)d_in[2];
  const float* w_enc    = (const float*)d_in[3];
  const float* w_dec    = (const float*)d_in[4];
  const float* enc_W0   = (const float*)d_in[5];
  const float* enc_b0   = (const float*)d_in[6];
  const float* enc_W1   = (const float*)d_in[7];
  const float* enc_b1   = (const float*)d_in[8];
  const float* dec_W0   = (const float*)d_in[9];
  const float* dec_b0   = (const float*)d_in[10];
  const float* dec_W1   = (const float*)d_in[11];
  const float* dec_b1   = (const float*)d_in[12];
  const float* t_W0     = (const float*)d_in[13];
  const float* t_b0     = (const float*)d_in[14];
  const float* t_W1     = (const float*)d_in[15];
  const float* t_b1     = (const float*)d_in[16];
  const float* lv_enc   = (const float*)d_in[17];
  const float* lv_dec   = (const float*)d_in[18];
  const float* t_logvar = (const float*)d_in[19];

  float* ws     = (float*)d_ws;
  float* z_past = ws;                         // 163840 f32
  float* mu_t   = z_past + 163840;            // 40960
  float* z_t    = mu_t + 40960;               // 40960
  float* rec_p  = z_t + 40960;                // 2560
  float* kl_p   = rec_p + 2560;               // 320
  float* em     = kl_p + 320;                 // 25600
  float* mu_all = em + 25600;                 // 204800
  float* yTb    = mu_all + 204800;            // 655360
  short* Abf    = (short*)(yTb + 655360);     // 5*2560*256
  short* PtE    = Abf + 5 * NSAMP * NDX;      // 5*1024*256
  short* QtD    = PtE + 5 * 1024 * NDX;       // 5*256*64*32
  short* TtB    = QtD + 5 * NDX * NH * 32;    // 80*64*320
  short* gated  = TtB + NM * NH * NTM;        // 80*512*320 (26.2 MB)

  k_prepW<<<8180, 256, 0, stream>>>(
      x, y, Abf, w_enc, enc_W0, PtE, w_dec, dec_W0, QtD, mask_p, em, t_W0, TtB, yTb);

  k_enc_mfma<<<dim3(NSAMP / 128, 4, ND), 512, 0, stream>>>(
      Abf, PtE, enc_b0, enc_W1, enc_b1, mu_all);
  k_noise<<<NSAMP * NM / 256, 256, 0, stream>>>(mu_all, lv_enc, z_past, mu_t, z_t);
  k_gated<<<NM * NB * 80 / 256, 256, 0, stream>>>(em, z_past, gated);
  k_trans_mfma<<<dim3(NB / 128, NM), 512, 0, stream>>>(
      gated, TtB, t_b0, t_W1, t_b1, lv_enc, t_logvar, mu_t, kl_p);
  k_dec_mfma<<<dim3(2, NDX, ND), 256, 0, stream>>>(
      z_t, QtD, yTb, dec_b0, dec_W1, dec_b1, lv_dec, rec_p);
  k_reduce<<<1, 256, 0, stream>>>(rec_p, kl_p, (float*)d_out);
}

// Round 8
// 80.076 us; speedup vs baseline: 8.0404x; 1.1223x over previous
//
#include <hip/hip_runtime.h>
#include <cstdint>

// ---- problem dims ----
constexpr int NB = 512, NTAU = 4, ND = 5, NDX = 256, NDZ = 16, NH = 64;
constexpr int NM  = ND * NDZ;          // 80
constexpr int NTM = NTAU * NM;         // 320
constexpr int NSAMP = NB * NTAU + NB;  // 2560 (past samples then t samples)
constexpr float LOG2PI_F = 1.8378770664093453f;

typedef __attribute__((ext_vector_type(8))) short bf16x8;
typedef __attribute__((ext_vector_type(4))) float f32x4;

// ---- counter-based RNG (distribution-exact stand-in for jax.random) ----
__device__ __forceinline__ unsigned long long mix64(unsigned long long z) {
  z += 0x9E3779B97F4A7C15ull;
  z = (z ^ (z >> 30)) * 0xBF58476D1CE4E5B9ull;
  z = (z ^ (z >> 27)) * 0x94D049BB133111EBull;
  return z ^ (z >> 31);
}
__device__ __forceinline__ float u01f(unsigned long long h) {
  return ((float)(unsigned)(h >> 40) + 0.5f) * (1.0f / 16777216.0f);
}
__device__ __forceinline__ float rng_normal(unsigned long long salt, unsigned long long idx) {
  float u1 = u01f(mix64(salt + 2ull * idx));
  float u2 = u01f(mix64(salt + 2ull * idx + 1ull));
  float r = sqrtf(-2.0f * logf(u1));
  return r * cosf(6.283185307179586f * u2);
}
constexpr unsigned long long SALT_ADJ = 0x1000000000000ull;
constexpr unsigned long long SALT_EP  = 0x2000000000000ull;
constexpr unsigned long long SALT_ET  = 0x3000000000000ull;

__device__ __forceinline__ short f2bf(float f) {
  unsigned u = __float_as_uint(f);
  unsigned r = (u + 0x7FFFu + ((u >> 16) & 1u)) >> 16;
  return (short)r;
}

// =====================================================================
// k_prepW: operand materialization, one launch. block ranges:
// [0,1600) A vec8, [1600,2240) P vec8, [2240,2560) Q, [2560,2660) EM,
// [2660,3060) T, [3060,3700) yT
// =====================================================================
__global__ __launch_bounds__(256) void k_prepW(
    const float* __restrict__ x, const float* __restrict__ y, short* __restrict__ Abf,
    const float* __restrict__ w_enc, const float* __restrict__ eW0, short* __restrict__ PtE,
    const float* __restrict__ w_dec, const float* __restrict__ dW0, short* __restrict__ QtD,
    const float* __restrict__ mask_param, float* __restrict__ em,
    const float* __restrict__ tW0, short* __restrict__ TtB,
    float* __restrict__ yT)
{
  __shared__ short lds[64][65];
  const int bid = blockIdx.x;
  if (bid < 1600) {
    // Abf[d][s][x0..x0+7] vectorized
    int e0 = (bid * 256 + threadIdx.x) * 8;
    int d = e0 / (NSAMP * NDX);
    int r = e0 % (NSAMP * NDX);
    int s = r >> 8, x0 = r & 255;
    const float* src = (s < NB * NTAU)
        ? &x[((size_t)s * ND + d) * NDX + x0]
        : &y[((size_t)(s - NB * NTAU) * ND + d) * NDX + x0];
    float4 f0 = *(const float4*)src;
    float4 f1 = *(const float4*)(src + 4);
    bf16x8 o;
    o[0] = f2bf(f0.x); o[1] = f2bf(f0.y); o[2] = f2bf(f0.z); o[3] = f2bf(f0.w);
    o[4] = f2bf(f1.x); o[5] = f2bf(f1.y); o[6] = f2bf(f1.z); o[7] = f2bf(f1.w);
    *(bf16x8*)&Abf[e0] = o;
  } else if (bid < 2240) {
    // PtE[d][col=z*64+h][x0..x0+7] = w_enc[d,z,x] * eW0[z,x,h], vec8
    int e0 = ((bid - 1600) * 256 + threadIdx.x) * 8;
    int d = e0 / (1024 * NDX);
    int r = e0 % (1024 * NDX);
    int col = r >> 8, x0 = r & 255;
    int z = col >> 6, h = col & 63;
    const float* wep = &w_enc[((size_t)d * NDZ + z) * NDX + x0];
    float4 w0 = *(const float4*)wep;
    float4 w1 = *(const float4*)(wep + 4);
    const float* w0base = &eW0[((size_t)z * NDX + x0) * NH + h];
    bf16x8 o;
    o[0] = f2bf(w0.x * w0base[0 * NH]); o[1] = f2bf(w0.y * w0base[1 * NH]);
    o[2] = f2bf(w0.z * w0base[2 * NH]); o[3] = f2bf(w0.w * w0base[3 * NH]);
    o[4] = f2bf(w1.x * w0base[4 * NH]); o[5] = f2bf(w1.y * w0base[5 * NH]);
    o[6] = f2bf(w1.z * w0base[6 * NH]); o[7] = f2bf(w1.w * w0base[7 * NH]);
    *(bf16x8*)&PtE[e0] = o;
  } else if (bid < 2560) {
    int t = (bid - 2240) * 256 + threadIdx.x;
    int d = t / (NDX * NH);
    int r = t % (NDX * NH);
    int xx = r >> 6, h = r & 63;
    size_t base = (size_t)t * 32;
    #pragma unroll
    for (int z = 0; z < NDZ; ++z)
      QtD[base + z] = f2bf(w_dec[((size_t)d * NDX + xx) * NDZ + z] *
                           dW0[((size_t)xx * NDZ + z) * NH + h]);
    #pragma unroll
    for (int z = NDZ; z < 32; ++z) QtD[base + z] = 0;
  } else if (bid < 2660) {
    int idx = (bid - 2560) * 256 + threadIdx.x;
    em[idx] = expf(-mask_param[idx]);
  } else if (bid < 3060) {
    int r = bid - 2660;
    int kt = r % 5, m = r / 5;
    int k0 = kt * 64;
    for (int idx = threadIdx.x; idx < 64 * 64; idx += 256) {
      int hh = idx & 63, kk = idx >> 6;
      lds[kk][hh] = f2bf(tW0[((size_t)m * NTM + k0 + kk) * NH + hh]);
    }
    __syncthreads();
    for (int idx = threadIdx.x; idx < 64 * 64; idx += 256) {
      int kk = idx & 63, hh = idx >> 6;
      TtB[((size_t)m * NH + hh) * NTM + k0 + kk] = lds[kk][hh];
    }
  } else {
    // yT[d][xx][b] = y[b][d][xx], 4 b's per thread
    int e0 = ((bid - 3060) * 256 + threadIdx.x) * 4;
    int d = e0 / (NDX * NB);
    int rem = e0 % (NDX * NB);
    int xx = rem >> 9, b0 = rem & 511;
    float4 o;
    o.x = y[((size_t)(b0 + 0) * ND + d) * NDX + xx];
    o.y = y[((size_t)(b0 + 1) * ND + d) * NDX + xx];
    o.z = y[((size_t)(b0 + 2) * ND + d) * NDX + xx];
    o.w = y[((size_t)(b0 + 3) * ND + d) * NDX + xx];
    *(float4*)&yT[e0] = o;
  }
}

// =====================================================================
// encoder GEMM: 512 thr (8 waves x 16 rows = 128 samples), 4-z loop,
// LDS-shared B per z. grid (20 sb, 4 zq, 5 d)
// =====================================================================
__global__ __launch_bounds__(512) void k_enc_mfma(
    const short* __restrict__ Abf, const short* __restrict__ PtE,
    const float* __restrict__ b0, const float* __restrict__ W1,
    const float* __restrict__ b1, float* __restrict__ mu_all)
{
  __shared__ __align__(16) short Bs[64 * 264];

  const int d = blockIdx.z, zq = blockIdx.y;
  const int s0 = blockIdx.x * 128;
  const int tid = threadIdx.x;
  const int w = tid >> 6, l = tid & 63;
  const int lrow = l & 15, g = l >> 4;

  const short* Arow = Abf + ((size_t)(d * NSAMP + s0 + w * 16 + lrow)) * NDX + g * 8;
  bf16x8 a[8];
  #pragma unroll
  for (int ks = 0; ks < 8; ++ks) a[ks] = *(const bf16x8*)(Arow + ks * 32);

  const int stg_row = tid >> 3;        // 0..63
  const int stg_c   = (tid & 7) * 32;  // 32-short chunk

  for (int zi = 0; zi < 4; ++zi) {
    const int z = zq * 4 + zi;
    {
      const short* src = PtE + ((size_t)(d * 1024 + z * 64 + stg_row)) * NDX + stg_c;
      short* dst = Bs + stg_row * 264 + stg_c;
      #pragma unroll
      for (int j = 0; j < 4; ++j)
        *(bf16x8*)(dst + j * 8) = *(const bf16x8*)(src + j * 8);
    }
    __syncthreads();

    f32x4 acc[4] = {};
    #pragma unroll
    for (int nt = 0; nt < 4; ++nt) {
      const short* Brow = Bs + (nt * 16 + lrow) * 264 + g * 8;
      #pragma unroll
      for (int ks = 0; ks < 8; ++ks) {
        bf16x8 bv = *(const bf16x8*)(Brow + ks * 32);
        acc[nt] = __builtin_amdgcn_mfma_f32_16x16x32_bf16(a[ks], bv, acc[nt], 0, 0, 0);
      }
    }

    float b0v[4], w1v[4];
    #pragma unroll
    for (int nt = 0; nt < 4; ++nt) {
      int h = nt * 16 + lrow;
      b0v[nt] = b0[z * NH + h];
      w1v[nt] = W1[z * NH + h];
    }
    const float b1v = b1[z];
    #pragma unroll
    for (int reg = 0; reg < 4; ++reg) {
      float v = 0.0f;
      #pragma unroll
      for (int nt = 0; nt < 4; ++nt) {
        float hv = acc[nt][reg] + b0v[nt];
        hv = fmaxf(hv, 0.01f * hv);
        v += hv * w1v[nt];
      }
      #pragma unroll
      for (int off = 1; off < 16; off <<= 1) v += __shfl_xor(v, off, 16);
      if (lrow == 0) {
        int s = s0 + w * 16 + g * 4 + reg;
        mu_all[(size_t)s * NM + d * NDZ + z] = v + b1v;
      }
    }
    __syncthreads();
  }
}

// =====================================================================
// reparameterization: one thread per (s, m) element
// =====================================================================
__global__ __launch_bounds__(256) void k_noise(
    const float* __restrict__ mu_all, const float* __restrict__ lve,
    float* __restrict__ z_past, float* __restrict__ mu_t, float* __restrict__ z_t)
{
  int i = blockIdx.x * 256 + threadIdx.x;   // < 2560*80
  int s = i / NM, m = i - s * NM;
  int d = m >> 4;
  float mu = mu_all[i];
  float qs = expf(0.5f * lve[d]);
  if (s < NB * NTAU) {
    float eps = rng_normal(SALT_EP, (unsigned long long)s * NM + m);
    z_past[i] = mu + qs * eps;
  } else {
    int b = s - NB * NTAU;
    float eps = rng_normal(SALT_ET, (unsigned long long)b * NM + m);
    size_t o = (size_t)b * NM + m;
    mu_t[o] = mu;
    z_t[o]  = mu + qs * eps;
  }
}

// =====================================================================
// transition GEMM + KL with REGISTER-DIRECT gating:
// A-fragment a[ks][j] = bf16(adj(brow, tm0+j) * z_past[brow][tm0+j]),
// tm0 = g*8 + ks*32 (8-aligned, never crosses a t boundary).
// Hash stream identical to the old k_gated (aibase, +2, +4, +6).
// 512 thr (8 waves x 16 b-rows); TtB panel + em staged in LDS.
// grid (4 bq, 80 m)
// =====================================================================
__global__ __launch_bounds__(512) void k_trans_mfma(
    const float* __restrict__ em, const float* __restrict__ z_past,
    const short* __restrict__ TtB,
    const float* __restrict__ tb0, const float* __restrict__ tW1,
    const float* __restrict__ tb1, const float* __restrict__ lve,
    const float* __restrict__ t_logvar, const float* __restrict__ mu_t,
    float* __restrict__ kl_partial)
{
  __shared__ __align__(16) short Bls[64 * 328];
  __shared__ float ems[NTM];
  __shared__ float klb[8];

  const int m = blockIdx.y;
  const int b0 = blockIdx.x * 128;
  const int tid = threadIdx.x;
  const int w = tid >> 6, l = tid & 63;
  const int lrow = l & 15, g = l >> 4;

  // stage em[t][m][s] -> ems[tm]
  for (int i = tid; i < NTM; i += 512) {
    int t = i / NM, s = i - t * NM;
    ems[i] = em[(t * NM + m) * NM + s];
  }
  // stage B panel: TtB[m][h][k] -> Bls[h*328 + k]
  {
    const int r = tid >> 3;
    const int c0 = (tid & 7) * 40;
    const short* src = TtB + ((size_t)(m * NH + r)) * NTM + c0;
    short* dst = Bls + r * 328 + c0;
    #pragma unroll
    for (int j = 0; j < 5; ++j)
      *(bf16x8*)(dst + j * 8) = *(const bf16x8*)(src + j * 8);
  }
  __syncthreads();

  // build A fragments with inline gumbel-sigmoid gating
  const int brow = b0 + w * 16 + lrow;
  const float* zrow = z_past + (size_t)brow * NTM;
  bf16x8 a[10];
  #pragma unroll
  for (int ks = 0; ks < 10; ++ks) {
    const int tm0 = g * 8 + ks * 32;
    const int t = tm0 / NM;
    const int s0 = tm0 - t * NM;
    unsigned long long aibase =
        ((unsigned long long)((brow * NTAU + t) * NM + m)) * NM + s0;
    unsigned long long h0 = mix64(SALT_ADJ + aibase);
    unsigned long long h1 = mix64(SALT_ADJ + aibase + 2);
    unsigned long long h2 = mix64(SALT_ADJ + aibase + 4);
    unsigned long long h3 = mix64(SALT_ADJ + aibase + 6);
    float u[8];
    u[0] = ((float)(unsigned)(h0 >> 40) + 0.5f) * (1.0f / 16777216.0f);
    u[1] = ((float)((unsigned)(h0 >> 16) & 0xFFFFFFu) + 0.5f) * (1.0f / 16777216.0f);
    u[2] = ((float)(unsigned)(h1 >> 40) + 0.5f) * (1.0f / 16777216.0f);
    u[3] = ((float)((unsigned)(h1 >> 16) & 0xFFFFFFu) + 0.5f) * (1.0f / 16777216.0f);
    u[4] = ((float)(unsigned)(h2 >> 40) + 0.5f) * (1.0f / 16777216.0f);
    u[5] = ((float)((unsigned)(h2 >> 16) & 0xFFFFFFu) + 0.5f) * (1.0f / 16777216.0f);
    u[6] = ((float)(unsigned)(h3 >> 40) + 0.5f) * (1.0f / 16777216.0f);
    u[7] = ((float)((unsigned)(h3 >> 16) & 0xFFFFFFu) + 0.5f) * (1.0f / 16777216.0f);
    float4 z0 = *(const float4*)(zrow + tm0);
    float4 z1 = *(const float4*)(zrow + tm0 + 4);
    const float* zvp0 = &z0.x;
    const float* zvp1 = &z1.x;
    #pragma unroll
    for (int j = 0; j < 8; ++j) {
      float uu = fminf(fmaxf(u[j], 1e-6f), 1.0f - 1e-6f);
      float e = ems[tm0 + j];
      float den = fmaf(e, 1.0f - uu, uu);
      float adj = uu * __builtin_amdgcn_rcpf(den);
      float zv = (j < 4) ? zvp0[j] : zvp1[j - 4];
      a[ks][j] = f2bf(adj * zv);
    }
  }

  f32x4 acc[4] = {};
  #pragma unroll
  for (int nt = 0; nt < 4; ++nt) {
    const short* Brow = Bls + (nt * 16 + lrow) * 328 + g * 8;
    #pragma unroll
    for (int ks = 0; ks < 10; ++ks) {
      bf16x8 bv = *(const bf16x8*)(Brow + ks * 32);
      acc[nt] = __builtin_amdgcn_mfma_f32_16x16x32_bf16(a[ks], bv, acc[nt], 0, 0, 0);
    }
  }

  float b0v[4], w1v[4];
  #pragma unroll
  for (int nt = 0; nt < 4; ++nt) {
    int h = nt * 16 + lrow;
    b0v[nt] = tb0[m * NH + h];
    w1v[nt] = tW1[m * NH + h];
  }

  const int d = m >> 4;
  const float lv_t = t_logvar[m];
  const float lv_e = lve[d];
  const float inv2var = 0.5f * expf(-lv_t);
  const float qvar = expf(lv_e);
  const float cterm = 0.5f * lv_t - 0.5f * lv_e - 0.5f;
  const float bv1 = tb1[m];

  float klw = 0.0f;
  #pragma unroll
  for (int reg = 0; reg < 4; ++reg) {
    float v = 0.0f;
    #pragma unroll
    for (int nt = 0; nt < 4; ++nt) {
      float hv = acc[nt][reg] + b0v[nt];
      hv = fmaxf(hv, 0.01f * hv);
      v += hv * w1v[nt];
    }
    #pragma unroll
    for (int off = 1; off < 16; off <<= 1) v += __shfl_xor(v, off, 16);
    if (lrow == 0) {
      int b = b0 + w * 16 + g * 4 + reg;
      float pz = v + bv1;
      float diff = mu_t[(size_t)b * NM + m] - pz;
      klw += cterm + (qvar + diff * diff) * inv2var;
    }
  }
  klw += __shfl_xor(klw, 16, 64);
  klw += __shfl_xor(klw, 32, 64);

  if (l == 0) klb[w] = klw;
  __syncthreads();
  if (tid == 0) {
    float s = 0.f;
    #pragma unroll
    for (int i = 0; i < 8; ++i) s += klb[i];
    kl_partial[blockIdx.x * NM + m] = s;
  }
}

// =====================================================================
// decoder: K=32 padded MFMA, fused recon partial sums (yT float4 reads)
// grid (2, 256 xx, 5 d), block 256
// =====================================================================
__global__ __launch_bounds__(256) void k_dec_mfma(
    const float* __restrict__ zt, const short* __restrict__ QtD,
    const float* __restrict__ yT, const float* __restrict__ db0,
    const float* __restrict__ dW1, const float* __restrict__ db1,
    const float* __restrict__ lvd, float* __restrict__ rec_partial)
{
  const int d = blockIdx.z, xx = blockIdx.y, mb = blockIdx.x;
  const int w = threadIdx.x >> 6, l = threadIdx.x & 63;
  const int lrow = l & 15, g = l >> 4;

  bf16x8 bfr[4];
  const short* Bbase = QtD + ((size_t)((d * NDX + xx) * NH)) * 32;
  #pragma unroll
  for (int nt = 0; nt < 4; ++nt)
    bfr[nt] = *(const bf16x8*)(Bbase + (nt * 16 + lrow) * 32 + g * 8);

  f32x4 acc[4][4] = {};
  #pragma unroll
  for (int mt = 0; mt < 4; ++mt) {
    int b = mb * 256 + w * 64 + mt * 16 + lrow;
    bf16x8 a = {0, 0, 0, 0, 0, 0, 0, 0};
    if (g < 2) {
      const float* zp = zt + (size_t)b * NM + d * NDZ + g * 8;
      float4 f0 = *(const float4*)zp;
      float4 f1 = *(const float4*)(zp + 4);
      a[0] = f2bf(f0.x); a[1] = f2bf(f0.y); a[2] = f2bf(f0.z); a[3] = f2bf(f0.w);
      a[4] = f2bf(f1.x); a[5] = f2bf(f1.y); a[6] = f2bf(f1.z); a[7] = f2bf(f1.w);
    }
    #pragma unroll
    for (int nt = 0; nt < 4; ++nt)
      acc[mt][nt] = __builtin_amdgcn_mfma_f32_16x16x32_bf16(a, bfr[nt], acc[mt][nt], 0, 0, 0);
  }

  float db0v[4], dW1v[4];
  #pragma unroll
  for (int nt = 0; nt < 4; ++nt) {
    int h = nt * 16 + lrow;
    db0v[nt] = db0[xx * NH + h];
    dW1v[nt] = dW1[xx * NH + h];
  }
  const float lv = lvd[d];
  const float inv_std = expf(-0.5f * lv);
  const float cterm = -0.5f * lv - 0.5f * LOG2PI_F;
  const float b1v = db1[xx];

  float racc = 0.0f;
  #pragma unroll
  for (int mt = 0; mt < 4; ++mt) {
    float rs[4];
    #pragma unroll
    for (int reg = 0; reg < 4; ++reg) {
      float v = 0.0f;
      #pragma unroll
      for (int nt = 0; nt < 4; ++nt) {
        float hv = acc[mt][nt][reg] + db0v[nt];
        hv = fmaxf(hv, 0.01f * hv);
        v += hv * dW1v[nt];
      }
      #pragma unroll
      for (int off = 1; off < 16; off <<= 1) v += __shfl_xor(v, off, 16);
      rs[reg] = v;
    }
    if (lrow == 0) {
      int b = mb * 256 + w * 64 + mt * 16 + g * 4;
      float4 yv = *(const float4*)&yT[((size_t)d * NDX + xx) * NB + b];
      const float* yvp = &yv.x;
      #pragma unroll
      for (int reg = 0; reg < 4; ++reg) {
        float px = rs[reg] + b1v;
        float e = (yvp[reg] - px) * inv_std;
        racc += -0.5f * e * e + cterm;
      }
    }
  }
  racc += __shfl_xor(racc, 16, 64);
  racc += __shfl_xor(racc, 32, 64);

  __shared__ float rb[4];
  if (l == 0) rb[w] = racc;
  __syncthreads();
  if (threadIdx.x == 0)
    rec_partial[((size_t)d * NDX + xx) * 2 + mb] = rb[0] + rb[1] + rb[2] + rb[3];
}

// =====================================================================
// final reduction -> loss = (sum_kl - sum_recon) / B
// =====================================================================
__global__ __launch_bounds__(256) void k_reduce(
    const float* __restrict__ rp, const float* __restrict__ kp,
    float* __restrict__ out)
{
  __shared__ float sr[4], sk[4];
  float r = 0.f, k = 0.f;
  for (int i = threadIdx.x; i < 2560; i += 256) r += rp[i];
  for (int i = threadIdx.x; i < 320; i += 256) k += kp[i];
  #pragma unroll
  for (int off = 32; off; off >>= 1) {
    r += __shfl_xor(r, off, 64);
    k += __shfl_xor(k, off, 64);
  }
  int wv = threadIdx.x >> 6;
  if ((threadIdx.x & 63) == 0) { sr[wv] = r; sk[wv] = k; }
  __syncthreads();
  if (threadIdx.x == 0) {
    float R = sr[0] + sr[1] + sr[2] + sr[3];
    float K = sk[0] + sk[1] + sk[2] + sk[3];
    out[0] = (K - R) / (float)NB;
  }
}

// =====================================================================
extern "C" void kernel_launch(void* const* d_in, const int* in_sizes, int n_in,
                              void* d_out, int out_size, void* d_ws, size_t ws_size,
                              hipStream_t stream) {
  (void)in_sizes; (void)n_in; (void)out_size; (void)ws_size;
  const float* x        = (const float*)d_in[0];
  const float* y        = (const float*)d_in[1];
  const float* mask_p   = (const float*)d_in[2];
  const float* w_enc    = (const float*)d_in[3];
  const float* w_dec    = (const float*)d_in[4];
  const float* enc_W0   = (const float*)d_in[5];
  const float* enc_b0   = (const float*)d_in[6];
  const float* enc_W1   = (const float*)d_in[7];
  const float* enc_b1   = (const float*)d_in[8];
  const float* dec_W0   = (const float*)d_in[9];
  const float* dec_b0   = (const float*)d_in[10];
  const float* dec_W1   = (const float*)d_in[11];
  const float* dec_b1   = (const float*)d_in[12];
  const float* t_W0     = (const float*)d_in[13];
  const float* t_b0     = (const float*)d_in[14];
  const float* t_W1     = (const float*)d_in[15];
  const float* t_b1     = (const float*)d_in[16];
  const float* lv_enc   = (const float*)d_in[17];
  const float* lv_dec   = (const float*)d_in[18];
  const float* t_logvar = (const float*)d_in[19];

  float* ws     = (float*)d_ws;
  float* z_past = ws;                         // 163840 f32
  float* mu_t   = z_past + 163840;            // 40960
  float* z_t    = mu_t + 40960;               // 40960
  float* rec_p  = z_t + 40960;                // 2560
  float* kl_p   = rec_p + 2560;               // 320
  float* em     = kl_p + 320;                 // 25600
  float* mu_all = em + 25600;                 // 204800
  float* yTb    = mu_all + 204800;            // 655360
  short* Abf    = (short*)(yTb + 655360);     // 5*2560*256
  short* PtE    = Abf + 5 * NSAMP * NDX;      // 5*1024*256
  short* QtD    = PtE + 5 * 1024 * NDX;       // 5*256*64*32
  short* TtB    = QtD + 5 * NDX * NH * 32;    // 80*64*320

  k_prepW<<<3700, 256, 0, stream>>>(
      x, y, Abf, w_enc, enc_W0, PtE, w_dec, dec_W0, QtD, mask_p, em, t_W0, TtB, yTb);

  k_enc_mfma<<<dim3(NSAMP / 128, 4, ND), 512, 0, stream>>>(
      Abf, PtE, enc_b0, enc_W1, enc_b1, mu_all);
  k_noise<<<NSAMP * NM / 256, 256, 0, stream>>>(mu_all, lv_enc, z_past, mu_t, z_t);
  k_trans_mfma<<<dim3(NB / 128, NM), 512, 0, stream>>>(
      em, z_past, TtB, t_b0, t_W1, t_b1, lv_enc, t_logvar, mu_t, kl_p);
  k_dec_mfma<<<dim3(2, NDX, ND), 256, 0, stream>>>(
      z_t, QtD, yTb, dec_b0, dec_W1, dec_b1, lv_dec, rec_p);
  k_reduce<<<1, 256, 0, stream>>>(rec_p, kl_p, (float*)d_out);
}

// Round 9
// 72.436 us; speedup vs baseline: 8.8885x; 1.1055x over previous
//
#include <hip/hip_runtime.h>
#include <cstdint>

// ---- problem dims ----
constexpr int NB = 512, NTAU = 4, ND = 5, NDX = 256, NDZ = 16, NH = 64;
constexpr int NM  = ND * NDZ;          // 80
constexpr int NTM = NTAU * NM;         // 320
constexpr int NSAMP = NB * NTAU + NB;  // 2560 (past samples then t samples)
constexpr float LOG2PI_F = 1.8378770664093453f;

typedef __attribute__((ext_vector_type(8))) short bf16x8;
typedef __attribute__((ext_vector_type(4))) float f32x4;

// ---- counter-based RNG (distribution-exact stand-in for jax.random) ----
__device__ __forceinline__ unsigned long long mix64(unsigned long long z) {
  z += 0x9E3779B97F4A7C15ull;
  z = (z ^ (z >> 30)) * 0xBF58476D1CE4E5B9ull;
  z = (z ^ (z >> 27)) * 0x94D049BB133111EBull;
  return z ^ (z >> 31);
}
__device__ __forceinline__ float u01f(unsigned long long h) {
  return ((float)(unsigned)(h >> 40) + 0.5f) * (1.0f / 16777216.0f);
}
__device__ __forceinline__ float rng_normal(unsigned long long salt, unsigned long long idx) {
  float u1 = u01f(mix64(salt + 2ull * idx));
  float u2 = u01f(mix64(salt + 2ull * idx + 1ull));
  float r = sqrtf(-2.0f * logf(u1));
  return r * cosf(6.283185307179586f * u2);
}
constexpr unsigned long long SALT_ADJ = 0x1000000000000ull;
constexpr unsigned long long SALT_EP  = 0x2000000000000ull;
constexpr unsigned long long SALT_ET  = 0x3000000000000ull;

__device__ __forceinline__ short f2bf(float f) {
  unsigned u = __float_as_uint(f);
  unsigned r = (u + 0x7FFFu + ((u >> 16) & 1u)) >> 16;
  return (short)r;
}

// =====================================================================
// k_prepW: operand materialization. block ranges:
// [0,640) P vec8, [640,960) Q, [960,1060) EM, [1060,1460) T, [1460,2100) yT
// =====================================================================
__global__ __launch_bounds__(256) void k_prepW(
    const float* __restrict__ y,
    const float* __restrict__ w_enc, const float* __restrict__ eW0, short* __restrict__ PtE,
    const float* __restrict__ w_dec, const float* __restrict__ dW0, short* __restrict__ QtD,
    const float* __restrict__ mask_param, float* __restrict__ em,
    const float* __restrict__ tW0, short* __restrict__ TtB,
    float* __restrict__ yT)
{
  __shared__ short lds[64][65];
  const int bid = blockIdx.x;
  if (bid < 640) {
    // PtE[d][col=z*64+h][x0..x0+7] = w_enc[d,z,x] * eW0[z,x,h], vec8
    int e0 = (bid * 256 + threadIdx.x) * 8;
    int d = e0 / (1024 * NDX);
    int r = e0 % (1024 * NDX);
    int col = r >> 8, x0 = r & 255;
    int z = col >> 6, h = col & 63;
    const float* wep = &w_enc[((size_t)d * NDZ + z) * NDX + x0];
    float4 w0 = *(const float4*)wep;
    float4 w1 = *(const float4*)(wep + 4);
    const float* w0base = &eW0[((size_t)z * NDX + x0) * NH + h];
    bf16x8 o;
    o[0] = f2bf(w0.x * w0base[0 * NH]); o[1] = f2bf(w0.y * w0base[1 * NH]);
    o[2] = f2bf(w0.z * w0base[2 * NH]); o[3] = f2bf(w0.w * w0base[3 * NH]);
    o[4] = f2bf(w1.x * w0base[4 * NH]); o[5] = f2bf(w1.y * w0base[5 * NH]);
    o[6] = f2bf(w1.z * w0base[6 * NH]); o[7] = f2bf(w1.w * w0base[7 * NH]);
    *(bf16x8*)&PtE[e0] = o;
  } else if (bid < 960) {
    int t = (bid - 640) * 256 + threadIdx.x;
    int d = t / (NDX * NH);
    int r = t % (NDX * NH);
    int xx = r >> 6, h = r & 63;
    size_t base = (size_t)t * 32;
    #pragma unroll
    for (int z = 0; z < NDZ; ++z)
      QtD[base + z] = f2bf(w_dec[((size_t)d * NDX + xx) * NDZ + z] *
                           dW0[((size_t)xx * NDZ + z) * NH + h]);
    #pragma unroll
    for (int z = NDZ; z < 32; ++z) QtD[base + z] = 0;
  } else if (bid < 1060) {
    int idx = (bid - 960) * 256 + threadIdx.x;
    em[idx] = expf(-mask_param[idx]);
  } else if (bid < 1460) {
    int r = bid - 1060;
    int kt = r % 5, m = r / 5;
    int k0 = kt * 64;
    for (int idx = threadIdx.x; idx < 64 * 64; idx += 256) {
      int hh = idx & 63, kk = idx >> 6;
      lds[kk][hh] = f2bf(tW0[((size_t)m * NTM + k0 + kk) * NH + hh]);
    }
    __syncthreads();
    for (int idx = threadIdx.x; idx < 64 * 64; idx += 256) {
      int kk = idx & 63, hh = idx >> 6;
      TtB[((size_t)m * NH + hh) * NTM + k0 + kk] = lds[kk][hh];
    }
  } else {
    // yT[d][xx][b] = y[b][d][xx], 4 b's per thread
    int e0 = ((bid - 1460) * 256 + threadIdx.x) * 4;
    int d = e0 / (NDX * NB);
    int rem = e0 % (NDX * NB);
    int xx = rem >> 9, b0 = rem & 511;
    float4 o;
    o.x = y[((size_t)(b0 + 0) * ND + d) * NDX + xx];
    o.y = y[((size_t)(b0 + 1) * ND + d) * NDX + xx];
    o.z = y[((size_t)(b0 + 2) * ND + d) * NDX + xx];
    o.w = y[((size_t)(b0 + 3) * ND + d) * NDX + xx];
    *(float4*)&yT[e0] = o;
  }
}

// =====================================================================
// encoder GEMM + fused reparameterization.
// grid (20 sb, 4 zq, 5 d), 512 thr (8 waves x 16 rows = 128 samples).
// A read f32 direct (inline f2bf), B staged in LDS per z, mu in LDS,
// final phase: all 512 threads do 1 RNG each and write z_past/mu_t/z_t.
// =====================================================================
__global__ __launch_bounds__(512) void k_enc_mfma(
    const float* __restrict__ x, const float* __restrict__ y,
    const short* __restrict__ PtE,
    const float* __restrict__ b0, const float* __restrict__ W1,
    const float* __restrict__ b1, const float* __restrict__ lve,
    float* __restrict__ z_past, float* __restrict__ mu_t, float* __restrict__ z_t)
{
  __shared__ __align__(16) short Bs[64 * 264];
  __shared__ float mu_s[128][4];

  const int d = blockIdx.z, zq = blockIdx.y;
  const int s0 = blockIdx.x * 128;
  const int tid = threadIdx.x;
  const int w = tid >> 6, l = tid & 63;
  const int lrow = l & 15, g = l >> 4;

  // A fragments: read f32 row, convert inline (bit-identical to old Abf path)
  const int srow = s0 + w * 16 + lrow;
  const float* Asrc = (srow < NB * NTAU)
      ? &x[((size_t)srow * ND + d) * NDX]
      : &y[((size_t)(srow - NB * NTAU) * ND + d) * NDX];
  bf16x8 a[8];
  #pragma unroll
  for (int ks = 0; ks < 8; ++ks) {
    const float* p = Asrc + g * 8 + ks * 32;
    float4 f0 = *(const float4*)p;
    float4 f1 = *(const float4*)(p + 4);
    a[ks][0] = f2bf(f0.x); a[ks][1] = f2bf(f0.y);
    a[ks][2] = f2bf(f0.z); a[ks][3] = f2bf(f0.w);
    a[ks][4] = f2bf(f1.x); a[ks][5] = f2bf(f1.y);
    a[ks][6] = f2bf(f1.z); a[ks][7] = f2bf(f1.w);
  }

  const int stg_row = tid >> 3;        // 0..63
  const int stg_c   = (tid & 7) * 32;  // 32-short chunk

  for (int zi = 0; zi < 4; ++zi) {
    const int z = zq * 4 + zi;
    {
      const short* src = PtE + ((size_t)(d * 1024 + z * 64 + stg_row)) * NDX + stg_c;
      short* dst = Bs + stg_row * 264 + stg_c;
      #pragma unroll
      for (int j = 0; j < 4; ++j)
        *(bf16x8*)(dst + j * 8) = *(const bf16x8*)(src + j * 8);
    }
    __syncthreads();

    f32x4 acc[4] = {};
    #pragma unroll
    for (int nt = 0; nt < 4; ++nt) {
      const short* Brow = Bs + (nt * 16 + lrow) * 264 + g * 8;
      #pragma unroll
      for (int ks = 0; ks < 8; ++ks) {
        bf16x8 bv = *(const bf16x8*)(Brow + ks * 32);
        acc[nt] = __builtin_amdgcn_mfma_f32_16x16x32_bf16(a[ks], bv, acc[nt], 0, 0, 0);
      }
    }

    float b0v[4], w1v[4];
    #pragma unroll
    for (int nt = 0; nt < 4; ++nt) {
      int h = nt * 16 + lrow;
      b0v[nt] = b0[z * NH + h];
      w1v[nt] = W1[z * NH + h];
    }
    const float b1v = b1[z];
    #pragma unroll
    for (int reg = 0; reg < 4; ++reg) {
      float v = 0.0f;
      #pragma unroll
      for (int nt = 0; nt < 4; ++nt) {
        float hv = acc[nt][reg] + b0v[nt];
        hv = fmaxf(hv, 0.01f * hv);
        v += hv * w1v[nt];
      }
      #pragma unroll
      for (int off = 1; off < 16; off <<= 1) v += __shfl_xor(v, off, 16);
      if (lrow == 0)
        mu_s[w * 16 + g * 4 + reg][zi] = v + b1v;
    }
    __syncthreads();
  }

  // fused reparameterization: 512 threads x 1 element (sl, zi)
  {
    const int sl = tid >> 2, zi = tid & 3;
    const int z = zq * 4 + zi;
    const int s = s0 + sl;
    const int m = d * NDZ + z;
    float mu = mu_s[sl][zi];
    float qs = expf(0.5f * lve[d]);
    if (s < NB * NTAU) {
      float eps = rng_normal(SALT_EP, (unsigned long long)s * NM + m);
      z_past[(size_t)s * NM + m] = mu + qs * eps;
    } else {
      int b = s - NB * NTAU;
      float eps = rng_normal(SALT_ET, (unsigned long long)b * NM + m);
      size_t o = (size_t)b * NM + m;
      mu_t[o] = mu;
      z_t[o]  = mu + qs * eps;
    }
  }
}

// =====================================================================
// k_tail: blocks [0,320) = transition GEMM + KL (register-direct gating);
//         blocks [320,1600) = decoder + recon. 512 thr both.
// =====================================================================
__global__ __launch_bounds__(512) void k_tail(
    const float* __restrict__ em, const float* __restrict__ z_past,
    const short* __restrict__ TtB,
    const float* __restrict__ tb0, const float* __restrict__ tW1,
    const float* __restrict__ tb1, const float* __restrict__ lve,
    const float* __restrict__ t_logvar, const float* __restrict__ mu_t,
    float* __restrict__ kl_partial,
    const float* __restrict__ zt, const short* __restrict__ QtD,
    const float* __restrict__ yT, const float* __restrict__ db0,
    const float* __restrict__ dW1, const float* __restrict__ db1,
    const float* __restrict__ lvd, float* __restrict__ rec_partial)
{
  __shared__ __align__(16) short Bls[64 * 328];
  __shared__ float ems[NTM];
  __shared__ float redb[8];

  const int bid = blockIdx.x;
  const int tid = threadIdx.x;

  if (bid < 320) {
    // ---------------- transition + KL ----------------
    const int m = bid >> 2;
    const int b0 = (bid & 3) * 128;
    const int w = tid >> 6, l = tid & 63;
    const int lrow = l & 15, g = l >> 4;

    for (int i = tid; i < NTM; i += 512) {
      int t = i / NM, s = i - t * NM;
      ems[i] = em[(t * NM + m) * NM + s];
    }
    {
      const int r = tid >> 3;
      const int c0 = (tid & 7) * 40;
      const short* src = TtB + ((size_t)(m * NH + r)) * NTM + c0;
      short* dst = Bls + r * 328 + c0;
      #pragma unroll
      for (int j = 0; j < 5; ++j)
        *(bf16x8*)(dst + j * 8) = *(const bf16x8*)(src + j * 8);
    }
    __syncthreads();

    const int brow = b0 + w * 16 + lrow;
    const float* zrow = z_past + (size_t)brow * NTM;
    bf16x8 a[10];
    #pragma unroll
    for (int ks = 0; ks < 10; ++ks) {
      const int tm0 = g * 8 + ks * 32;
      const int t = tm0 / NM;
      const int s0 = tm0 - t * NM;
      unsigned long long aibase =
          ((unsigned long long)((brow * NTAU + t) * NM + m)) * NM + s0;
      unsigned long long h0 = mix64(SALT_ADJ + aibase);
      unsigned long long h1 = mix64(SALT_ADJ + aibase + 2);
      unsigned long long h2 = mix64(SALT_ADJ + aibase + 4);
      unsigned long long h3 = mix64(SALT_ADJ + aibase + 6);
      float u[8];
      u[0] = ((float)(unsigned)(h0 >> 40) + 0.5f) * (1.0f / 16777216.0f);
      u[1] = ((float)((unsigned)(h0 >> 16) & 0xFFFFFFu) + 0.5f) * (1.0f / 16777216.0f);
      u[2] = ((float)(unsigned)(h1 >> 40) + 0.5f) * (1.0f / 16777216.0f);
      u[3] = ((float)((unsigned)(h1 >> 16) & 0xFFFFFFu) + 0.5f) * (1.0f / 16777216.0f);
      u[4] = ((float)(unsigned)(h2 >> 40) + 0.5f) * (1.0f / 16777216.0f);
      u[5] = ((float)((unsigned)(h2 >> 16) & 0xFFFFFFu) + 0.5f) * (1.0f / 16777216.0f);
      u[6] = ((float)(unsigned)(h3 >> 40) + 0.5f) * (1.0f / 16777216.0f);
      u[7] = ((float)((unsigned)(h3 >> 16) & 0xFFFFFFu) + 0.5f) * (1.0f / 16777216.0f);
      float4 z0 = *(const float4*)(zrow + tm0);
      float4 z1 = *(const float4*)(zrow + tm0 + 4);
      const float* zvp0 = &z0.x;
      const float* zvp1 = &z1.x;
      #pragma unroll
      for (int j = 0; j < 8; ++j) {
        float uu = fminf(fmaxf(u[j], 1e-6f), 1.0f - 1e-6f);
        float e = ems[tm0 + j];
        float den = fmaf(e, 1.0f - uu, uu);
        float adj = uu * __builtin_amdgcn_rcpf(den);
        float zv = (j < 4) ? zvp0[j] : zvp1[j - 4];
        a[ks][j] = f2bf(adj * zv);
      }
    }

    f32x4 acc[4] = {};
    #pragma unroll
    for (int nt = 0; nt < 4; ++nt) {
      const short* Brow = Bls + (nt * 16 + lrow) * 328 + g * 8;
      #pragma unroll
      for (int ks = 0; ks < 10; ++ks) {
        bf16x8 bv = *(const bf16x8*)(Brow + ks * 32);
        acc[nt] = __builtin_amdgcn_mfma_f32_16x16x32_bf16(a[ks], bv, acc[nt], 0, 0, 0);
      }
    }

    float b0v[4], w1v[4];
    #pragma unroll
    for (int nt = 0; nt < 4; ++nt) {
      int h = nt * 16 + lrow;
      b0v[nt] = tb0[m * NH + h];
      w1v[nt] = tW1[m * NH + h];
    }

    const int d = m >> 4;
    const float lv_t = t_logvar[m];
    const float lv_e = lve[d];
    const float inv2var = 0.5f * expf(-lv_t);
    const float qvar = expf(lv_e);
    const float cterm = 0.5f * lv_t - 0.5f * lv_e - 0.5f;
    const float bv1 = tb1[m];

    float klw = 0.0f;
    #pragma unroll
    for (int reg = 0; reg < 4; ++reg) {
      float v = 0.0f;
      #pragma unroll
      for (int nt = 0; nt < 4; ++nt) {
        float hv = acc[nt][reg] + b0v[nt];
        hv = fmaxf(hv, 0.01f * hv);
        v += hv * w1v[nt];
      }
      #pragma unroll
      for (int off = 1; off < 16; off <<= 1) v += __shfl_xor(v, off, 16);
      if (lrow == 0) {
        int b = b0 + w * 16 + g * 4 + reg;
        float pz = v + bv1;
        float diff = mu_t[(size_t)b * NM + m] - pz;
        klw += cterm + (qvar + diff * diff) * inv2var;
      }
    }
    klw += __shfl_xor(klw, 16, 64);
    klw += __shfl_xor(klw, 32, 64);

    if (l == 0) redb[w] = klw;
    __syncthreads();
    if (tid == 0) {
      float s = 0.f;
      #pragma unroll
      for (int i = 0; i < 8; ++i) s += redb[i];
      kl_partial[(bid & 3) * NM + m] = s;
    }
  } else {
    // ---------------- decoder + recon ----------------
    const int idx = bid - 320;
    const int d = idx >> 8, xx = idx & 255;
    const int w8 = tid >> 6, l = tid & 63;
    const int mb = w8 >> 2, w = w8 & 3;
    const int lrow = l & 15, g = l >> 4;

    bf16x8 bfr[4];
    const short* Bbase = QtD + ((size_t)((d * NDX + xx) * NH)) * 32;
    #pragma unroll
    for (int nt = 0; nt < 4; ++nt)
      bfr[nt] = *(const bf16x8*)(Bbase + (nt * 16 + lrow) * 32 + g * 8);

    f32x4 acc[4][4] = {};
    #pragma unroll
    for (int mt = 0; mt < 4; ++mt) {
      int b = mb * 256 + w * 64 + mt * 16 + lrow;
      bf16x8 a = {0, 0, 0, 0, 0, 0, 0, 0};
      if (g < 2) {
        const float* zp = zt + (size_t)b * NM + d * NDZ + g * 8;
        float4 f0 = *(const float4*)zp;
        float4 f1 = *(const float4*)(zp + 4);
        a[0] = f2bf(f0.x); a[1] = f2bf(f0.y); a[2] = f2bf(f0.z); a[3] = f2bf(f0.w);
        a[4] = f2bf(f1.x); a[5] = f2bf(f1.y); a[6] = f2bf(f1.z); a[7] = f2bf(f1.w);
      }
      #pragma unroll
      for (int nt = 0; nt < 4; ++nt)
        acc[mt][nt] = __builtin_amdgcn_mfma_f32_16x16x32_bf16(a, bfr[nt], acc[mt][nt], 0, 0, 0);
    }

    float db0v[4], dW1v[4];
    #pragma unroll
    for (int nt = 0; nt < 4; ++nt) {
      int h = nt * 16 + lrow;
      db0v[nt] = db0[xx * NH + h];
      dW1v[nt] = dW1[xx * NH + h];
    }
    const float lv = lvd[d];
    const float inv_std = expf(-0.5f * lv);
    const float cterm = -0.5f * lv - 0.5f * LOG2PI_F;
    const float b1v = db1[xx];

    float racc = 0.0f;
    #pragma unroll
    for (int mt = 0; mt < 4; ++mt) {
      float rs[4];
      #pragma unroll
      for (int reg = 0; reg < 4; ++reg) {
        float v = 0.0f;
        #pragma unroll
        for (int nt = 0; nt < 4; ++nt) {
          float hv = acc[mt][nt][reg] + db0v[nt];
          hv = fmaxf(hv, 0.01f * hv);
          v += hv * dW1v[nt];
        }
        #pragma unroll
        for (int off = 1; off < 16; off <<= 1) v += __shfl_xor(v, off, 16);
        rs[reg] = v;
      }
      if (lrow == 0) {
        int b = mb * 256 + w * 64 + mt * 16 + g * 4;
        float4 yv = *(const float4*)&yT[((size_t)d * NDX + xx) * NB + b];
        const float* yvp = &yv.x;
        #pragma unroll
        for (int reg = 0; reg < 4; ++reg) {
          float px = rs[reg] + b1v;
          float e = (yvp[reg] - px) * inv_std;
          racc += -0.5f * e * e + cterm;
        }
      }
    }
    racc += __shfl_xor(racc, 16, 64);
    racc += __shfl_xor(racc, 32, 64);

    if (l == 0) redb[w8] = racc;
    __syncthreads();
    if (tid == 0) {
      float s = 0.f;
      #pragma unroll
      for (int i = 0; i < 8; ++i) s += redb[i];
      rec_partial[(size_t)d * NDX + xx] = s;
    }
  }
}

// =====================================================================
// final reduction -> loss = (sum_kl - sum_recon) / B
// =====================================================================
__global__ __launch_bounds__(256) void k_reduce(
    const float* __restrict__ rp, const float* __restrict__ kp,
    float* __restrict__ out)
{
  __shared__ float sr[4], sk[4];
  float r = 0.f, k = 0.f;
  for (int i = threadIdx.x; i < 1280; i += 256) r += rp[i];
  for (int i = threadIdx.x; i < 320; i += 256) k += kp[i];
  #pragma unroll
  for (int off = 32; off; off >>= 1) {
    r += __shfl_xor(r, off, 64);
    k += __shfl_xor(k, off, 64);
  }
  int wv = threadIdx.x >> 6;
  if ((threadIdx.x & 63) == 0) { sr[wv] = r; sk[wv] = k; }
  __syncthreads();
  if (threadIdx.x == 0) {
    float R = sr[0] + sr[1] + sr[2] + sr[3];
    float K = sk[0] + sk[1] + sk[2] + sk[3];
    out[0] = (K - R) / (float)NB;
  }
}

// =====================================================================
extern "C" void kernel_launch(void* const* d_in, const int* in_sizes, int n_in,
                              void* d_out, int out_size, void* d_ws, size_t ws_size,
                              hipStream_t stream) {
  (void)in_sizes; (void)n_in; (void)out_size; (void)ws_size;
  const float* x        = (const float*)d_in[0];
  const float* y        = (const float*)d_in[1];
  const float* mask_p   = (const float*)d_in[2];
  const float* w_enc    = (const float*)d_in[3];
  const float* w_dec    = (const float*)d_in[4];
  const float* enc_W0   = (const float*)d_in[5];
  const float* enc_b0   = (const float*)d_in[6];
  const float* enc_W1   = (const float*)d_in[7];
  const float* enc_b1   = (const float*)d_in[8];
  const float* dec_W0   = (const float*)d_in[9];
  const float* dec_b0   = (const float*)d_in[10];
  const float* dec_W1   = (const float*)d_in[11];
  const float* dec_b1   = (const float*)d_in[12];
  const float* t_W0     = (const float*)d_in[13];
  const float* t_b0     = (const float*)d_in[14];
  const float* t_W1     = (const float*)d_in[15];
  const float* t_b1     = (const float*)d_in[16];
  const float* lv_enc   = (const float*)d_in[17];
  const float* lv_dec   = (const float*)d_in[18];
  const float* t_logvar = (const float*)d_in[19];

  float* ws     = (float*)d_ws;
  float* z_past = ws;                         // 163840 f32
  float* mu_t   = z_past + 163840;            // 40960
  float* z_t    = mu_t + 40960;               // 40960
  float* rec_p  = z_t + 40960;                // 1280
  float* kl_p   = rec_p + 1280;               // 320
  float* em     = kl_p + 320;                 // 25600
  float* yTb    = em + 25600;                 // 655360
  short* PtE    = (short*)(yTb + 655360);     // 5*1024*256
  short* QtD    = PtE + 5 * 1024 * NDX;       // 5*256*64*32
  short* TtB    = QtD + 5 * NDX * NH * 32;    // 80*64*320

  k_prepW<<<2100, 256, 0, stream>>>(
      y, w_enc, enc_W0, PtE, w_dec, dec_W0, QtD, mask_p, em, t_W0, TtB, yTb);

  k_enc_mfma<<<dim3(NSAMP / 128, 4, ND), 512, 0, stream>>>(
      x, y, PtE, enc_b0, enc_W1, enc_b1, lv_enc, z_past, mu_t, z_t);
  k_tail<<<1600, 512, 0, stream>>>(
      em, z_past, TtB, t_b0, t_W1, t_b1, lv_enc, t_logvar, mu_t, kl_p,
      z_t, QtD, yTb, dec_b0, dec_W1, dec_b1, lv_dec, rec_p);
  k_reduce<<<1, 256, 0, stream>>>(rec_p, kl_p, (float*)d_out);
}